// Round 20
// baseline (440.784 us; speedup 1.0000x reference)
//
#include <hip/hip_runtime.h>
#include <hip/hip_bf16.h>

typedef unsigned short u16;
typedef unsigned char u8;
typedef __attribute__((ext_vector_type(8))) short bf16x8;
typedef __attribute__((ext_vector_type(4))) float f32x4;
typedef __attribute__((ext_vector_type(2))) float f32x2;

#define DEV __device__ __forceinline__

// ---------- bf16 helpers (storage only; math in f32) ----------
DEV float b2f(u16 s){ return __uint_as_float(((unsigned)s) << 16); }
DEV u16 f2b(float f){
    unsigned u = __float_as_uint(f);
    u = u + 0x7fffu + ((u >> 16) & 1u);   // round-to-nearest-even
    return (u16)(u >> 16);
}
// fp8 e4m3 (OCP) helpers
DEV u8 f2f8(float v){
    int r = __builtin_amdgcn_cvt_pk_fp8_f32(v, v, 0, false);
    return (u8)(r & 0xff);
}
DEV unsigned f2f8x4(float a, float b, float c, float d){
    int lo = __builtin_amdgcn_cvt_pk_fp8_f32(a, b, 0, false);
    int r  = __builtin_amdgcn_cvt_pk_fp8_f32(c, d, lo, true);
    return (unsigned)r;
}
DEV void storeElem(float* p, float v){ *p = v; }
DEV void storeElem(u16* p, float v){ *p = f2b(v); }
DEV void storeElem(u8* p, float v){ *p = f2f8(v); }

template<int ACT> DEV float actf(float x){
    if (ACT == 1) return fmaxf(x, 0.f);
    if (ACT == 2) return 0.5f * x * (1.f + erff(x * 0.70710678118654752f)); // exact GELU
    return x;
}

// async global(16B/lane) -> LDS (wave-uniform base + lane*16)
DEV void gload16(const void* g, void* l){
    __builtin_amdgcn_global_load_lds(
        (const __attribute__((address_space(1))) void*)g,
        (__attribute__((address_space(3))) void*)l, 16, 0, 0);
}

// ---------- feature transpose: (n,C,H,W) f32 -> (n,H,W,C) fp8 ----------
__global__ void transpose_feat(const float* __restrict__ in, u8* __restrict__ out,
                               int H, int W){
    int total = 6 * H * W * 32;                // 4-channel units
    int lin = blockIdx.x * 256 + threadIdx.x;
    if (lin >= total) return;
    int c4   = (lin & 31) * 4;
    int pix  = lin >> 5;
    int x    = pix % W;
    int rest = pix / W;
    int y    = rest % H;
    int n    = rest / H;
    int HW   = H * W;
    size_t ib = ((size_t)(n * 128 + c4) * H + y) * W + x;
    unsigned v4 = f2f8x4(in[ib], in[ib + (size_t)HW],
                         in[ib + (size_t)2 * HW], in[ib + (size_t)3 * HW]);
    *(unsigned*)&out[(size_t)pix * 128 + c4] = v4;
}

// ---------- one-time weight prep ----------
// W[K][N] f32 -> WT[N][K] bf16
__global__ void prep_wt(const float* __restrict__ w, u16* __restrict__ o, int K, int N){
    int id = blockIdx.x * 256 + threadIdx.x;
    if (id >= K * N) return;
    int n = id / K, k = id % K;
    o[id] = f2b(w[(size_t)k * N + n]);
}
// W[K][N] f32 -> WT[N][K] fp8
__global__ void prep_wt_f8(const float* __restrict__ w, u8* __restrict__ o, int K, int N){
    int id = blockIdx.x * 256 + threadIdx.x;
    if (id >= K * N) return;
    int n = id / K, k = id % K;
    o[id] = f2f8(w[(size_t)k * N + n]);
}
// f32 -> bf16 elementwise (4/thread): bev_q snapshot
__global__ void prep_cvt16(const float* __restrict__ src, u16* __restrict__ dst, int n4){
    int i4 = blockIdx.x * 256 + threadIdx.x;
    if (i4 >= n4) return;
    float4 a = *(const float4*)&src[(size_t)i4 * 4];
    ushort4 v; v.x = f2b(a.x); v.y = f2b(a.y); v.z = f2b(a.z); v.w = f2b(a.w);
    *(ushort4*)&dst[(size_t)i4 * 4] = v;
}
// combined off/sw weight: owsT[32][128], obias[32]
__global__ void prep_osw_w(const float* __restrict__ off_w, const float* __restrict__ off_b,
                           const float* __restrict__ sw_w, const float* __restrict__ sw_b,
                           u16* __restrict__ owsT, float* __restrict__ obias){
    int id = blockIdx.x * 256 + threadIdx.x;   // 32*128 = 4096
    if (id >= 4096) return;
    int n = id >> 7, k = id & 127;
    float w = (n < 12) ? off_w[k * 12 + n] : (n < 28) ? sw_w[k * 16 + (n - 12)] : 0.f;
    owsT[n * 128 + k] = f2b(w);
    if (k == 0) obias[n] = (n < 12) ? off_b[n] : (n < 28) ? sw_b[n - 12] : 0.f;
}
// conv2_w (5,5,128,128)=[tap][ic][oc] f32 -> fragment-major fp8:
// byte offset = tap*16384 + ks*4096 + kg*1024 + oc*8 + j, ic = ks*32 + kg*8 + j
__global__ void prep_conv_w_f8(const float* __restrict__ w, u8* __restrict__ o){
    int id = blockIdx.x * 256 + threadIdx.x;   // 25*128*16 = 51200
    if (id >= 51200) return;
    int slot = id & 15;                        // slot = ks*4 + kg
    int oc   = (id >> 4) & 127;
    int tap  = id >> 11;
    int ks = slot >> 2, kg = slot & 3;
    int ic0 = ks * 32 + kg * 8;
    u8 tmp[8];
#pragma unroll
    for (int j = 0; j < 8; j++)
        tmp[j] = f2f8(w[((size_t)tap * 128 + ic0 + j) * 128 + oc]);
    *(long*)&o[(size_t)tap * 16384 + ks * 4096 + kg * 1024 + oc * 8] = *(long*)tmp;
}

// ---------- MFMA GEMM (bf16): C[M,Ntot] = act(A[M,K] @ BT[N,K]^T + bias) ----------
DEV void stage64(const u16* __restrict__ g, int ldk, u16* lds, int wv, int lane){
    const u16* gp = g + (size_t)(lane >> 3) * ldk + (lane & 7) * 8;
#pragma unroll
    for (int j = 0; j < 4; j++){
        int ch = wv + j * 4;                 // 16 chunks of 1KB (8 rows each)
        gload16(gp + (size_t)ch * 8 * ldk, lds + ch * 512);
    }
}
// fp8 staging: 128-row x 64B tile, pre-swizzled source (pair ^= (row>>1)&3)
DEV void stage64f8(const u8* __restrict__ g, int ldk, u8* lds, int wv, int lane){
    int rloc = lane >> 2;
#pragma unroll
    for (int j = 0; j < 2; j++){
        int ch = wv + j * 4;                 // 8 chunks of 1KB (16 rows each)
        int row = ch * 16 + rloc;
        int sp  = (lane & 3) ^ ((row >> 1) & 3);
        gload16(g + (size_t)row * ldk + sp * 16, lds + ch * 1024);
    }
}

// NBY>0: 1-D grid of 8*ceil(NBX/8)*NBY blocks (same-XCD N-grouping).
template<int K, int ACT, typename TOUT, int NBY = 0, int NBX = 0>
__global__ __launch_bounds__(256) void mfma_gemm(
    const u16* __restrict__ A, const u16* __restrict__ BT,
    const float* __restrict__ bias, TOUT* __restrict__ C, int Ntot){
    __shared__ u16 As[2][128 * 64];
    __shared__ u16 Bs[2][128 * 64];
    const int t = threadIdx.x, wv = t >> 6, lane = t & 63;
    int bx, by;
    if (NBY > 0){
        const int gpx = (NBX + 7) / 8;
        int xcd = blockIdx.x & 7, slot = blockIdx.x >> 3;
        bx = xcd * gpx + slot / NBY;
        by = slot % NBY;
        if (bx >= NBX) return;
    } else { bx = blockIdx.x; by = blockIdx.y; }
    const int r0 = bx * 128, n0 = by * 128;
    const int l15 = lane & 15, kg = lane >> 4;
    const int wr = (wv >> 1) * 64, wc = (wv & 1) * 64;
    f32x4 acc[4][4];
#pragma unroll
    for (int r = 0; r < 4; r++)
#pragma unroll
        for (int c = 0; c < 4; c++) acc[r][c] = (f32x4){0.f, 0.f, 0.f, 0.f};

    stage64(A + (size_t)r0 * K, K, As[0], wv, lane);
    stage64(BT + (size_t)n0 * K, K, Bs[0], wv, lane);
    __syncthreads();
    int buf = 0;
    for (int kc = 0; kc < K / 64; kc++){
        if (kc + 1 < K / 64){
            stage64(A + (size_t)r0 * K + (kc + 1) * 64, K, As[buf ^ 1], wv, lane);
            stage64(BT + (size_t)n0 * K + (kc + 1) * 64, K, Bs[buf ^ 1], wv, lane);
        }
#pragma unroll
        for (int ks = 0; ks < 2; ks++){
            bf16x8 af[4], bfr[4];
#pragma unroll
            for (int r = 0; r < 4; r++)
                af[r] = *(const bf16x8*)&As[buf][(wr + r * 16 + l15) * 64 + ks * 32 + kg * 8];
#pragma unroll
            for (int c = 0; c < 4; c++)
                bfr[c] = *(const bf16x8*)&Bs[buf][(wc + c * 16 + l15) * 64 + ks * 32 + kg * 8];
#pragma unroll
            for (int r = 0; r < 4; r++)
#pragma unroll
                for (int c = 0; c < 4; c++)
                    acc[r][c] = __builtin_amdgcn_mfma_f32_16x16x32_bf16(af[r], bfr[c], acc[r][c], 0, 0, 0);
        }
        __syncthreads();
        buf ^= 1;
    }
#pragma unroll
    for (int c = 0; c < 4; c++){
        int gcol = n0 + wc + c * 16 + l15;
        float bb = bias[gcol];
#pragma unroll
        for (int r = 0; r < 4; r++){
#pragma unroll
            for (int reg = 0; reg < 4; reg++){
                int grow = r0 + wr + r * 16 + kg * 4 + reg;
                storeElem(C + (size_t)grow * Ntot + gcol, actf<ACT>(acc[r][c][reg] + bb));
            }
        }
    }
}

// ---------- MFMA GEMM (fp8 e4m3 A/B): same tiling, halved LDS/traffic ----------
template<int K, int ACT, typename TOUT, int NBY = 0, int NBX = 0>
__global__ __launch_bounds__(256) void mfma_gemm_f8(
    const u8* __restrict__ A, const u8* __restrict__ BT,
    const float* __restrict__ bias, TOUT* __restrict__ C, int Ntot){
    __shared__ __align__(16) u8 As[2][128 * 64];
    __shared__ __align__(16) u8 Bs[2][128 * 64];
    const int t = threadIdx.x, wv = t >> 6, lane = t & 63;
    int bx, by;
    if (NBY > 0){
        const int gpx = (NBX + 7) / 8;
        int xcd = blockIdx.x & 7, slot = blockIdx.x >> 3;
        bx = xcd * gpx + slot / NBY;
        by = slot % NBY;
        if (bx >= NBX) return;
    } else { bx = blockIdx.x; by = blockIdx.y; }
    const int r0 = bx * 128, n0 = by * 128;
    const int l15 = lane & 15, kg = lane >> 4;
    const int wr = (wv >> 1) * 64, wc = (wv & 1) * 64;
    f32x4 acc[4][4];
#pragma unroll
    for (int r = 0; r < 4; r++)
#pragma unroll
        for (int c = 0; c < 4; c++) acc[r][c] = (f32x4){0.f, 0.f, 0.f, 0.f};

    stage64f8(A + (size_t)r0 * K, K, As[0], wv, lane);
    stage64f8(BT + (size_t)n0 * K, K, Bs[0], wv, lane);
    __syncthreads();
    int buf = 0;
    for (int kc = 0; kc < K / 64; kc++){
        if (kc + 1 < K / 64){
            stage64f8(A + (size_t)r0 * K + (kc + 1) * 64, K, As[buf ^ 1], wv, lane);
            stage64f8(BT + (size_t)n0 * K + (kc + 1) * 64, K, Bs[buf ^ 1], wv, lane);
        }
#pragma unroll
        for (int ks = 0; ks < 2; ks++){
            long af[4], bfr[4];
#pragma unroll
            for (int r = 0; r < 4; r++){
                int row = wr + r * 16 + l15;
                int s8 = (ks * 4 + kg) ^ (row & 6);
                af[r] = *(const long*)&As[buf][row * 64 + s8 * 8];
            }
#pragma unroll
            for (int c = 0; c < 4; c++){
                int row = wc + c * 16 + l15;
                int s8 = (ks * 4 + kg) ^ (row & 6);
                bfr[c] = *(const long*)&Bs[buf][row * 64 + s8 * 8];
            }
#pragma unroll
            for (int r = 0; r < 4; r++)
#pragma unroll
                for (int c = 0; c < 4; c++)
                    acc[r][c] = __builtin_amdgcn_mfma_f32_16x16x32_fp8_fp8(af[r], bfr[c], acc[r][c], 0, 0, 0);
        }
        __syncthreads();
        buf ^= 1;
    }
#pragma unroll
    for (int c = 0; c < 4; c++){
        int gcol = n0 + wc + c * 16 + l15;
        float bb = bias[gcol];
#pragma unroll
        for (int r = 0; r < 4; r++){
#pragma unroll
            for (int reg = 0; reg < 4; reg++){
                int grow = r0 + wr + r * 16 + kg * 4 + reg;
                storeElem(C + (size_t)grow * Ntot + gcol, actf<ACT>(acc[r][c][reg] + bb));
            }
        }
    }
}

// ---------- pos-embed GEMM (fused hid): pos = relu(bev_pos@W1+b1) @ W2^T + b2 ;
//            qpos16 = bf16(pos + bev_q). hid chunks computed on the fly into LDS.
__global__ __launch_bounds__(256) void mfma_pos(
    const float* __restrict__ bev_pos,
    const float* __restrict__ w1, const float* __restrict__ b1,
    const u16* __restrict__ BT, const float* __restrict__ bias,
    const float* __restrict__ bq,
    float* __restrict__ pos, u16* __restrict__ qp16){
    __shared__ u16 As[2][128 * 64];
    __shared__ u16 Bs[2][128 * 64];
    const int t = threadIdx.x, wv = t >> 6, lane = t & 63;
    const int r0 = blockIdx.x * 128;
    const int l15 = lane & 15, kg = lane >> 4;
    const int wr = (wv >> 1) * 64, wc = (wv & 1) * 64;
    f32x4 acc[4][4];
#pragma unroll
    for (int r = 0; r < 4; r++)
#pragma unroll
        for (int c = 0; c < 4; c++) acc[r][c] = (f32x4){0.f, 0.f, 0.f, 0.f};

    // hid chunk kc -> dst: 128 rows x 64 k (1024 tasks of 8 elems)
    auto hidchunk = [&](int kc, u16* dst){
#pragma unroll
        for (int i = 0; i < 4; i++){
            int task = i * 256 + t;
            int row = task >> 3, k8 = (task & 7) * 8;
            int grow = min(r0 + row, 39999);
            float p0 = bev_pos[grow * 3 + 0];
            float p1 = bev_pos[grow * 3 + 1];
            float p2 = bev_pos[grow * 3 + 2];
            int ch0 = kc * 64 + k8;
            u16 tmp[8];
#pragma unroll
            for (int j = 0; j < 8; j++){
                int ch = ch0 + j;
                float h = p0 * w1[ch] + p1 * w1[256 + ch] + p2 * w1[512 + ch] + b1[ch];
                tmp[j] = f2b(fmaxf(h, 0.f));
            }
            *(uint4*)&dst[row * 64 + k8] = *(uint4*)tmp;
        }
    };

    hidchunk(0, As[0]);
    stage64(BT, 256, Bs[0], wv, lane);
    __syncthreads();
    int buf = 0;
    for (int kc = 0; kc < 4; kc++){
        if (kc + 1 < 4){
            stage64(BT + (kc + 1) * 64, 256, Bs[buf ^ 1], wv, lane);
            hidchunk(kc + 1, As[buf ^ 1]);
        }
#pragma unroll
        for (int ks = 0; ks < 2; ks++){
            bf16x8 af[4], bfr[4];
#pragma unroll
            for (int r = 0; r < 4; r++)
                af[r] = *(const bf16x8*)&As[buf][(wr + r * 16 + l15) * 64 + ks * 32 + kg * 8];
#pragma unroll
            for (int c = 0; c < 4; c++)
                bfr[c] = *(const bf16x8*)&Bs[buf][(wc + c * 16 + l15) * 64 + ks * 32 + kg * 8];
#pragma unroll
            for (int r = 0; r < 4; r++)
#pragma unroll
                for (int c = 0; c < 4; c++)
                    acc[r][c] = __builtin_amdgcn_mfma_f32_16x16x32_bf16(af[r], bfr[c], acc[r][c], 0, 0, 0);
        }
        __syncthreads();
        buf ^= 1;
    }
#pragma unroll
    for (int c = 0; c < 4; c++){
        int gcol = wc + c * 16 + l15;
        float bb = bias[gcol];
#pragma unroll
        for (int r = 0; r < 4; r++){
#pragma unroll
            for (int reg = 0; reg < 4; reg++){
                int grow = r0 + wr + r * 16 + kg * 4 + reg;
                int growc = min(grow, 39999);          // bev_q is 40000 rows
                float v = acc[r][c][reg] + bb;
                pos[(size_t)grow * 128 + gcol]  = v;
                qp16[(size_t)grow * 128 + gcol] = f2b(v + bq[(size_t)growc * 128 + gcol]);
            }
        }
    }
}

// ---------- fused FFN + residual + LN: out = LN(q + relu(q16@W1+b1)@W2 + b2) ----------
// qin is bf16. AUXM: 0 = write outf f32 (final); 2 = write q16out bf16 + auxpos bf16(o+pos)
template<int AUXM>
__global__ __launch_bounds__(256) void mfma_ffn_ln(
    const u16* __restrict__ A, const u16* __restrict__ W1T,
    const float* __restrict__ b1, const u16* __restrict__ W2T,
    const float* __restrict__ b2, const u16* __restrict__ qin16,
    const float* __restrict__ gam, const float* __restrict__ bet,
    float* __restrict__ outf, u16* __restrict__ q16out, u16* __restrict__ auxpos,
    const float* __restrict__ pos, int Mlim){
    __shared__ u16 As[2][128 * 64];   // A tile, then h
    __shared__ u16 Bs[2][128 * 64];   // W1T, then W2T
    const int t = threadIdx.x, wv = t >> 6, lane = t & 63;
    const int r0 = blockIdx.x * 128;
    const int l15 = lane & 15, kg = lane >> 4;
    const int wr = wv * 32;
    f32x4 acc[2][8];
#pragma unroll
    for (int r = 0; r < 2; r++)
#pragma unroll
        for (int c = 0; c < 8; c++) acc[r][c] = (f32x4){0.f, 0.f, 0.f, 0.f};

    stage64(A + (size_t)r0 * 128, 128, As[0], wv, lane);
    stage64(A + (size_t)r0 * 128 + 64, 128, As[1], wv, lane);
    stage64(W1T, 128, Bs[0], wv, lane);
    stage64(W1T + 64, 128, Bs[1], wv, lane);
    __syncthreads();
    // GEMM1: h_acc = A @ W1^T
#pragma unroll
    for (int kc = 0; kc < 2; kc++){
#pragma unroll
        for (int ks = 0; ks < 2; ks++){
            bf16x8 af[2], bfr[8];
#pragma unroll
            for (int r = 0; r < 2; r++)
                af[r] = *(const bf16x8*)&As[kc][(wr + r * 16 + l15) * 64 + ks * 32 + kg * 8];
#pragma unroll
            for (int c = 0; c < 8; c++)
                bfr[c] = *(const bf16x8*)&Bs[kc][(c * 16 + l15) * 64 + ks * 32 + kg * 8];
#pragma unroll
            for (int r = 0; r < 2; r++)
#pragma unroll
                for (int c = 0; c < 8; c++)
                    acc[r][c] = __builtin_amdgcn_mfma_f32_16x16x32_bf16(af[r], bfr[c], acc[r][c], 0, 0, 0);
        }
    }
    __syncthreads();   // all reads of As/Bs complete
    // stage W2T (async) and write h = relu(acc + b1) into As
    stage64(W2T, 128, Bs[0], wv, lane);
    stage64(W2T + 64, 128, Bs[1], wv, lane);
#pragma unroll
    for (int c = 0; c < 8; c++){
        int col = c * 16 + l15;
        float bb1 = b1[col];
#pragma unroll
        for (int r = 0; r < 2; r++)
#pragma unroll
            for (int reg = 0; reg < 4; reg++){
                int rowl = wr + r * 16 + kg * 4 + reg;
                As[col >> 6][rowl * 64 + (col & 63)] = f2b(fmaxf(acc[r][c][reg] + bb1, 0.f));
            }
    }
    __syncthreads();
    // GEMM2: out = h @ W2^T
#pragma unroll
    for (int r = 0; r < 2; r++)
#pragma unroll
        for (int c = 0; c < 8; c++) acc[r][c] = (f32x4){0.f, 0.f, 0.f, 0.f};
#pragma unroll
    for (int kc = 0; kc < 2; kc++){
#pragma unroll
        for (int ks = 0; ks < 2; ks++){
            bf16x8 af[2], bfr[8];
#pragma unroll
            for (int r = 0; r < 2; r++)
                af[r] = *(const bf16x8*)&As[kc][(wr + r * 16 + l15) * 64 + ks * 32 + kg * 8];
#pragma unroll
            for (int c = 0; c < 8; c++)
                bfr[c] = *(const bf16x8*)&Bs[kc][(c * 16 + l15) * 64 + ks * 32 + kg * 8];
#pragma unroll
            for (int r = 0; r < 2; r++)
#pragma unroll
                for (int c = 0; c < 8; c++)
                    acc[r][c] = __builtin_amdgcn_mfma_f32_16x16x32_bf16(af[r], bfr[c], acc[r][c], 0, 0, 0);
        }
    }
    // epilogue: x = acc + b2 + qin; LN over 128 cols (within wave)
    float bb[8], gg[8], be[8];
#pragma unroll
    for (int c = 0; c < 8; c++){
        int col = c * 16 + l15;
        bb[c] = b2[col]; gg[c] = gam[col]; be[c] = bet[col];
    }
#pragma unroll
    for (int r = 0; r < 2; r++){
#pragma unroll
        for (int reg = 0; reg < 4; reg++){
            int grow = r0 + wr + r * 16 + kg * 4 + reg;
            const u16* qrow = qin16 + (size_t)grow * 128;
            float s = 0.f, q2 = 0.f;
#pragma unroll
            for (int c = 0; c < 8; c++){
                float x = acc[r][c][reg] + bb[c] + b2f(qrow[c * 16 + l15]);
                acc[r][c][reg] = x;
                s += x; q2 += x * x;
            }
#pragma unroll
            for (int m = 8; m >= 1; m >>= 1){
                s  += __shfl_xor(s, m, 64);
                q2 += __shfl_xor(q2, m, 64);
            }
            float mean = s * 0.0078125f;
            float var  = q2 * 0.0078125f - mean * mean;
            float rs   = rsqrtf(var + 1e-5f);
            bool wr_ok = grow < Mlim;
#pragma unroll
            for (int c = 0; c < 8; c++){
                float o = (acc[r][c][reg] - mean) * rs * gg[c] + be[c];
                int col = c * 16 + l15;
                if (wr_ok){
                    if (AUXM == 0){
                        outf[(size_t)grow * 128 + col] = o;
                    } else {
                        q16out[(size_t)grow * 128 + col] = f2b(o);
                        auxpos[(size_t)grow * 128 + col] = f2b(o + pos[(size_t)grow * 128 + col]);
                    }
                }
            }
        }
    }
}

// ---------- MFMA GEMM (fp8 A/B) fused residual(bf16) + LN -> bf16 out ----------
template<int K>
__global__ __launch_bounds__(256) void mfma_gemm_ln_f8(
    const u8* __restrict__ A, const u8* __restrict__ BT,
    const float* __restrict__ bias, const u16* __restrict__ qin16,
    const float* __restrict__ gam, const float* __restrict__ bet,
    u16* __restrict__ q16out, int Mlim){
    __shared__ __align__(16) u8 As[2][128 * 64];
    __shared__ __align__(16) u8 Bs[2][128 * 64];
    const int t = threadIdx.x, wv = t >> 6, lane = t & 63;
    const int r0 = blockIdx.x * 128;
    const int l15 = lane & 15, kg = lane >> 4;
    const int wr = wv * 32;
    f32x4 acc[2][8];
#pragma unroll
    for (int r = 0; r < 2; r++)
#pragma unroll
        for (int c = 0; c < 8; c++) acc[r][c] = (f32x4){0.f, 0.f, 0.f, 0.f};

    stage64f8(A + (size_t)r0 * K, K, As[0], wv, lane);
    stage64f8(BT, K, Bs[0], wv, lane);
    __syncthreads();
    int buf = 0;
    for (int kc = 0; kc < K / 64; kc++){
        if (kc + 1 < K / 64){
            stage64f8(A + (size_t)r0 * K + (kc + 1) * 64, K, As[buf ^ 1], wv, lane);
            stage64f8(BT + (kc + 1) * 64, K, Bs[buf ^ 1], wv, lane);
        }
#pragma unroll
        for (int ks = 0; ks < 2; ks++){
            long af[2], bfr[8];
#pragma unroll
            for (int r = 0; r < 2; r++){
                int row = wr + r * 16 + l15;
                int s8 = (ks * 4 + kg) ^ (row & 6);
                af[r] = *(const long*)&As[buf][row * 64 + s8 * 8];
            }
#pragma unroll
            for (int c = 0; c < 8; c++){
                int row = c * 16 + l15;
                int s8 = (ks * 4 + kg) ^ (row & 6);
                bfr[c] = *(const long*)&Bs[buf][row * 64 + s8 * 8];
            }
#pragma unroll
            for (int r = 0; r < 2; r++)
#pragma unroll
                for (int c = 0; c < 8; c++)
                    acc[r][c] = __builtin_amdgcn_mfma_f32_16x16x32_fp8_fp8(af[r], bfr[c], acc[r][c], 0, 0, 0);
        }
        __syncthreads();
        buf ^= 1;
    }
    float bb[8], gg[8], be[8];
#pragma unroll
    for (int c = 0; c < 8; c++){
        int col = c * 16 + l15;
        bb[c] = bias[col]; gg[c] = gam[col]; be[c] = bet[col];
    }
#pragma unroll
    for (int r = 0; r < 2; r++){
#pragma unroll
        for (int reg = 0; reg < 4; reg++){
            int grow = r0 + wr + r * 16 + kg * 4 + reg;
            const u16* qrow = qin16 + (size_t)grow * 128;
            float s = 0.f, q2 = 0.f;
#pragma unroll
            for (int c = 0; c < 8; c++){
                float x = acc[r][c][reg] + bb[c] + b2f(qrow[c * 16 + l15]);
                acc[r][c][reg] = x;
                s += x; q2 += x * x;
            }
#pragma unroll
            for (int m = 8; m >= 1; m >>= 1){
                s  += __shfl_xor(s, m, 64);
                q2 += __shfl_xor(q2, m, 64);
            }
            float mean = s * 0.0078125f;
            float var  = q2 * 0.0078125f - mean * mean;
            float rs   = rsqrtf(var + 1e-5f);
            bool wr_ok = grow < Mlim;
#pragma unroll
            for (int c = 0; c < 8; c++){
                float o = (acc[r][c][reg] - mean) * rs * gg[c] + be[c];
                if (wr_ok) q16out[(size_t)grow * 128 + c * 16 + l15] = f2b(o);
            }
        }
    }
}

// ---------- small MFMA GEMM: osw[M][32] = q16[M][128] @ owsT[32][128]^T + obias ----------
__global__ __launch_bounds__(256) void mfma_osw(
    const u16* __restrict__ A, const u16* __restrict__ BT,
    const float* __restrict__ bias, float* __restrict__ osw){
    __shared__ u16 As[2][128 * 64];   // [k-half][row*64 + k']
    __shared__ u16 Bs[2][32 * 64];
    const int t = threadIdx.x, wv = t >> 6, lane = t & 63;
    const int r0 = blockIdx.x * 128;
    const int l15 = lane & 15, kg = lane >> 4;
#pragma unroll
    for (int it = 0; it < 8; it++){
        int id = it * 256 + t;
        int row = id >> 4, slot = id & 15;
        uint4 v = *(const uint4*)&A[(size_t)(r0 + row) * 128 + slot * 8];
        *(uint4*)&As[slot >> 3][row * 64 + (slot & 7) * 8] = v;
    }
#pragma unroll
    for (int it = 0; it < 2; it++){
        int id = it * 256 + t;
        if (id < 512){
            int row = id >> 4, slot = id & 15;
            uint4 v = *(const uint4*)&BT[(size_t)row * 128 + slot * 8];
            *(uint4*)&Bs[slot >> 3][row * 64 + (slot & 7) * 8] = v;
        }
    }
    __syncthreads();
    f32x4 acc[2][2];
#pragma unroll
    for (int r = 0; r < 2; r++)
#pragma unroll
        for (int c = 0; c < 2; c++) acc[r][c] = (f32x4){0.f, 0.f, 0.f, 0.f};
#pragma unroll
    for (int ks = 0; ks < 4; ks++){
        int h = ks >> 1, koff = (ks & 1) * 32 + kg * 8;
        bf16x8 af[2], bfr[2];
#pragma unroll
        for (int r = 0; r < 2; r++)
            af[r] = *(const bf16x8*)&As[h][(wv * 32 + r * 16 + l15) * 64 + koff];
#pragma unroll
        for (int c = 0; c < 2; c++)
            bfr[c] = *(const bf16x8*)&Bs[h][(c * 16 + l15) * 64 + koff];
#pragma unroll
        for (int r = 0; r < 2; r++)
#pragma unroll
            for (int c = 0; c < 2; c++)
                acc[r][c] = __builtin_amdgcn_mfma_f32_16x16x32_bf16(af[r], bfr[c], acc[r][c], 0, 0, 0);
    }
#pragma unroll
    for (int c = 0; c < 2; c++){
        int gcol = c * 16 + l15;
        float bb = bias[gcol];
#pragma unroll
        for (int r = 0; r < 2; r++)
#pragma unroll
            for (int reg = 0; reg < 4; reg++){
                int grow = r0 + wv * 32 + r * 16 + kg * 4 + reg;
                osw[(size_t)grow * 32 + gcol] = acc[r][c][reg] + bb;
            }
    }
}

// ---------- projection v3: per (q,p) emit 16B entries {bf16 w x4, base, dxdy} ----------
__global__ __launch_bounds__(256) void proj_kernel(
    const float* __restrict__ osw, const float* __restrict__ bev_pos,
    const float* __restrict__ l2i, uint4* __restrict__ ent4, int* __restrict__ cntb){
    int id = blockIdx.x * 256 + threadIdx.x;   // 160000 total
    int qi = id >> 2, p = id & 3;
    const float* row = osw + (size_t)qi * 32;
    float px = bev_pos[qi * 3 + 0] * 100.f - 50.f + row[p * 3 + 0];
    float py = bev_pos[qi * 3 + 1] * 100.f - 50.f + row[p * 3 + 1];
    float pz = bev_pos[qi * 3 + 2] * 8.f   - 5.f  + row[p * 3 + 2];
    float lg[4];
#pragma unroll
    for (int l = 0; l < 4; l++) lg[l] = row[12 + p * 4 + l];
    float mx = fmaxf(fmaxf(lg[0], lg[1]), fmaxf(lg[2], lg[3]));
    float den = 0.f, sw[4];
#pragma unroll
    for (int l = 0; l < 4; l++){ sw[l] = expf(lg[l] - mx); den += sw[l]; }
    float inv = 1.f / den;
#pragma unroll
    for (int l = 0; l < 4; l++) sw[l] *= inv;

    const int HS[4] = {32, 16, 8, 4};
    const int WS[4] = {88, 44, 22, 11};
    const unsigned LOFF[4] = {0u, 2162688u, 2703360u, 2838528u};
    int cnt = 0;
    for (int cam = 0; cam < 6; cam++){
        const float* M = l2i + cam * 16;
        float t0 = M[0] * px + M[1] * py + M[2]  * pz + M[3];
        float t1 = M[4] * px + M[5] * py + M[6]  * pz + M[7];
        float z  = M[8] * px + M[9] * py + M[10] * pz + M[11];
        float zc = fmaxf(z, 1e-5f);
        float u = t0 / (zc * 704.f);
        float v = t1 / (zc * 256.f);
        if (!((z > 1e-5f) && u >= 0.f && u <= 1.f && v >= 0.f && v <= 1.f)) continue;
#pragma unroll
        for (int l = 0; l < 4; l++){
            const int Hl = HS[l], Wl = WS[l];
            float xx = u * (float)Wl - 0.5f;
            float yy = v * (float)Hl - 0.5f;
            float xf = floorf(xx), yf = floorf(yy);
            float wx = xx - xf, wy = yy - yf;
            int ix = (int)xf, iy = (int)yf;
            float sl = sw[l];
            float wx0 = (ix >= 0)      ? 1.f - wx : 0.f;
            float wx1 = (ix < Wl - 1)  ? wx       : 0.f;
            float wy0 = (iy >= 0)      ? 1.f - wy : 0.f;
            float wy1 = (iy < Hl - 1)  ? wy       : 0.f;
            int x0c = max(ix, 0), x1c = min(ix + 1, Wl - 1);
            int y0c = max(iy, 0), y1c = min(iy + 1, Hl - 1);
            unsigned base = LOFF[l] + (unsigned)cam * (unsigned)(Hl * Wl * 128)
                          + (unsigned)(y0c * Wl + x0c) * 128u;
            unsigned dxdy = (unsigned)((x1c - x0c) * 128)
                          | ((unsigned)((y1c - y0c) * Wl * 128) << 16);
            if (cnt < 8){
                uint4 e4;
                e4.x = (unsigned)f2b(sl * wx0 * wy0) | ((unsigned)f2b(sl * wx1 * wy0) << 16);
                e4.y = (unsigned)f2b(sl * wx0 * wy1) | ((unsigned)f2b(sl * wx1 * wy1) << 16);
                e4.z = base;
                e4.w = dxdy;
                ent4[(size_t)cnt * 160000 + id] = e4;
                cnt++;
            }
        }
    }
    cntb[id] = cnt;
}

// ---------- deformable sampling v5: fp8 features, 16B entries, 16 lanes/(q,p) ----------
DEV void fma8f8(float* acc, uint2 v, float w){
    f32x2 p0 = __builtin_amdgcn_cvt_pk_f32_fp8(v.x, false);
    f32x2 p1 = __builtin_amdgcn_cvt_pk_f32_fp8(v.x, true);
    f32x2 p2 = __builtin_amdgcn_cvt_pk_f32_fp8(v.y, false);
    f32x2 p3 = __builtin_amdgcn_cvt_pk_f32_fp8(v.y, true);
    acc[0] = fmaf(p0.x, w, acc[0]);
    acc[1] = fmaf(p0.y, w, acc[1]);
    acc[2] = fmaf(p1.x, w, acc[2]);
    acc[3] = fmaf(p1.y, w, acc[3]);
    acc[4] = fmaf(p2.x, w, acc[4]);
    acc[5] = fmaf(p2.y, w, acc[5]);
    acc[6] = fmaf(p3.x, w, acc[6]);
    acc[7] = fmaf(p3.y, w, acc[7]);
}

__global__ __launch_bounds__(256) void sample_kernel(
    const uint4* __restrict__ ent4, const int* __restrict__ cntb,
    const u8* __restrict__ ftbase, u8* __restrict__ flat){
    const int t = threadIdx.x;
    const int lane = t & 15;
    const int id = blockIdx.x * 16 + (t >> 4);
    const int d0 = lane * 8;
    const int cnt = cntb[id];
    float acc[8] = {0, 0, 0, 0, 0, 0, 0, 0};

    uint4 evA, evB;
    if (cnt > 0) evA = ent4[(size_t)id];
    for (int e = 0; e < cnt; e++){
        if (e + 1 < cnt) evB = ent4[(size_t)(e + 1) * 160000 + id];
        unsigned base = evA.z + (unsigned)d0;
        unsigned dx = evA.w & 0xffffu, dy = evA.w >> 16;
        uint2 v00 = *(const uint2*)(ftbase + base);
        uint2 v10 = *(const uint2*)(ftbase + base + dx);
        uint2 v01 = *(const uint2*)(ftbase + base + dy);
        uint2 v11 = *(const uint2*)(ftbase + base + dx + dy);
        fma8f8(acc, v00, b2f((u16)(evA.x & 0xffffu)));
        fma8f8(acc, v10, b2f((u16)(evA.x >> 16)));
        fma8f8(acc, v01, b2f((u16)(evA.y & 0xffffu)));
        fma8f8(acc, v11, b2f((u16)(evA.y >> 16)));
        evA = evB;
    }
    uint2 o;
    o.x = f2f8x4(acc[0], acc[1], acc[2], acc[3]);
    o.y = f2f8x4(acc[4], acc[5], acc[6], acc[7]);
    *(uint2*)&flat[(size_t)id * 128 + d0] = o;
}

// ---------- 5x5 conv via fp8 MFMA implicit GEMM, fused residual(bf16) + LN(n1) ----------
// 256 threads = 4 waves. Tile 64 px (8y x 8x) x 128 oc. Grid 25x25 = 625.
// Patch LDS stride 136B (17x8B): bank base = 2*pix mod 32 and the 16-lane A-read
// footprint has pix distinct mod 16 -> conflict-free WITHOUT any swizzle.
// Stores are two 8B ds_writes (<=2-way aliasing = free).
#define ALOAD(S, DST) if ((S) < 100){                                                 \
    const int tap_ = (S) >> 2, ks_ = (S) & 3;                                         \
    const int ky_ = tap_ / 5, kx_ = tap_ - ky_ * 5;                                   \
    const int s8_ = ks_ * 4 + kg;                                                     \
    _Pragma("unroll")                                                                 \
    for (int fb = 0; fb < 2; fb++){                                                   \
        _Pragma("unroll")                                                             \
        for (int fp = 0; fp < 2; fp++){                                               \
            int pr_ = fb * 4 + (l15 >> 2) + ky_;                                      \
            int pc_ = fp * 4 + (l15 & 3) + kx_;                                       \
            int pix_ = pr_ * 12 + pc_;                                                \
            DST[fb * 2 + fp] = *(const long*)((const char*)Ps + pix_ * 136 + s8_ * 8);\
        }                                                                             \
    }                                                                                 \
}
#define CMFMA(CURA, CURB) {                                                           \
    _Pragma("unroll")                                                                 \
    for (int fr = 0; fr < 4; fr++){                                                   \
        acc[fr][0] = __builtin_amdgcn_mfma_f32_16x16x32_fp8_fp8(CURA[fr], CURB[0], acc[fr][0], 0, 0, 0); \
        acc[fr][1] = __builtin_amdgcn_mfma_f32_16x16x32_fp8_fp8(CURA[fr], CURB[1], acc[fr][1], 0, 0, 0); \
    }                                                                                 \
}
#define LOADB(S, DST) if ((S) < 100){                                                 \
    const u8* wp_ = wfrag + ((S) >> 2) * 16384 + ((S) & 3) * 4096                     \
                   + kg * 1024 + (wc + l15) * 8;                                      \
    DST[0] = *(const long*)(wp_);                                                     \
    DST[1] = *(const long*)(wp_ + 128);                                               \
}

__global__ __launch_bounds__(256, 4) void conv5_ln(
    const u8* __restrict__ in,      // [200][200][128] fp8 (conv1 output)
    const u8* __restrict__ wfrag,   // frag-major fp8 weights
    const float* __restrict__ bias,
    const u16* __restrict__ qin16,  // residual input (bf16, 40000x128)
    const float* __restrict__ gam, const float* __restrict__ bet,
    u16* __restrict__ q16){
    __shared__ __align__(16) u8 Ps[144 * 136];   // 19584 B, stride-136 layout
    const int t = threadIdx.x, wv = t >> 6, lane = t & 63;
    const int bx = blockIdx.x % 25, by = blockIdx.x / 25;
    const int x0 = bx * 8, y0 = by * 8;
    const int l15 = lane & 15, kg = lane >> 4;
    const int wc = wv * 32;             // wave's 32-oc quarter

    // patch staging: 144 px x 8 slot16 of 16B = 1152 chunks (two 8B LDS writes)
#pragma unroll
    for (int it = 0; it < 5; it++){
        int id = it * 256 + t;
        if (id < 1152){
            int pix = id >> 3, slot = id & 7;
            int pr = pix / 12, pc = pix - pr * 12;
            int gy = y0 + pr - 2, gx = x0 + pc - 2;
            uint4 v = {0u, 0u, 0u, 0u};
            if (gy >= 0 && gy < 200 && gx >= 0 && gx < 200)
                v = *(const uint4*)&in[(size_t)(gy * 200 + gx) * 128 + slot * 16];
            char* dst = (char*)Ps + pix * 136 + slot * 16;
            uint2 lo; lo.x = v.x; lo.y = v.y;
            uint2 hi; hi.x = v.z; hi.y = v.w;
            *(uint2*)dst = lo;
            *(uint2*)(dst + 8) = hi;
        }
    }
    f32x4 acc[4][2];
#pragma unroll
    for (int r = 0; r < 4; r++){
        acc[r][0] = (f32x4){0.f, 0.f, 0.f, 0.f};
        acc[r][1] = (f32x4){0.f, 0.f, 0.f, 0.f};
    }

    // preload B steps 0..2 (depth-3)
    long b0[2], b1[2], b2[2], b3[2];
    LOADB(0, b0); LOADB(1, b1); LOADB(2, b2);
    __syncthreads();

    // preload A step 0
    long aA[4], aB[4];
    ALOAD(0, aA);

    // main loop: 100 quarter-tap steps, no barriers, 4-step unroll
    for (int i = 0; i < 25; i++){
        int s = i * 4;
        LOADB(s + 3, b3); ALOAD(s + 1, aB); CMFMA(aA, b0);
        LOADB(s + 4, b0); ALOAD(s + 2, aA); CMFMA(aB, b1);
        LOADB(s + 5, b1); ALOAD(s + 3, aB); CMFMA(aA, b2);
        LOADB(s + 6, b2); ALOAD(s + 4, aA); CMFMA(aB, b3);
    }
    __syncthreads();   // all waves done reading Ps before overlay

    // ---- fused residual + LayerNorm epilogue (Ps is dead; overlay partials) ----
    float* part = (float*)Ps;   // [64][4 waves][2] f32 = 2KB
    float bb[2], gg[2], be[2];
#pragma unroll
    for (int c = 0; c < 2; c++){
        int oc = wc + c * 16 + l15;
        bb[c] = bias[oc]; gg[c] = gam[oc]; be[c] = bet[oc];
    }
#pragma unroll
    for (int fb = 0; fb < 2; fb++){
#pragma unroll
        for (int fp = 0; fp < 2; fp++){
#pragma unroll
            for (int reg = 0; reg < 4; reg++){
                int py = fb * 4 + kg, px = fp * 4 + reg;
                int lp = py * 8 + px;
                int grow = (y0 + py) * 200 + x0 + px;
                const u16* qrow = qin16 + (size_t)grow * 128;
                float s = 0.f, q2 = 0.f;
#pragma unroll
                for (int c = 0; c < 2; c++){
                    float x = acc[fb * 2 + fp][c][reg] + bb[c] + b2f(qrow[wc + c * 16 + l15]);
                    acc[fb * 2 + fp][c][reg] = x;
                    s += x; q2 += x * x;
                }
#pragma unroll
                for (int msk = 8; msk >= 1; msk >>= 1){
                    s  += __shfl_xor(s, msk, 64);
                    q2 += __shfl_xor(q2, msk, 64);
                }
                if (l15 == 0){
                    part[lp * 8 + wv * 2 + 0] = s;
                    part[lp * 8 + wv * 2 + 1] = q2;
                }
            }
        }
    }
    __syncthreads();
#pragma unroll
    for (int fb = 0; fb < 2; fb++){
#pragma unroll
        for (int fp = 0; fp < 2; fp++){
#pragma unroll
            for (int reg = 0; reg < 4; reg++){
                int py = fb * 4 + kg, px = fp * 4 + reg;
                int lp = py * 8 + px;
                int grow = (y0 + py) * 200 + x0 + px;
                float s  = part[lp * 8 + 0] + part[lp * 8 + 2] + part[lp * 8 + 4] + part[lp * 8 + 6];
                float q2 = part[lp * 8 + 1] + part[lp * 8 + 3] + part[lp * 8 + 5] + part[lp * 8 + 7];
                float mean = s * 0.0078125f;
                float var  = q2 * 0.0078125f - mean * mean;
                float rs   = rsqrtf(var + 1e-5f);
#pragma unroll
                for (int c = 0; c < 2; c++){
                    int oc = wc + c * 16 + l15;
                    float o = (acc[fb * 2 + fp][c][reg] - mean) * rs * gg[c] + be[c];
                    q16[(size_t)grow * 128 + oc] = f2b(o);
                }
            }
        }
    }
}

// =======================================================================
extern "C" void kernel_launch(void* const* d_in, const int* in_sizes, int n_in,
                              void* d_out, int out_size, void* d_ws, size_t ws_size,
                              hipStream_t stream){
    const float* feat0   = (const float*)d_in[0];
    const float* feat1   = (const float*)d_in[1];
    const float* feat2   = (const float*)d_in[2];
    const float* feat3   = (const float*)d_in[3];
    const float* l2i     = (const float*)d_in[4];
    const float* bev_q   = (const float*)d_in[5];
    const float* bev_pos = (const float*)d_in[6];
    const float* pe_w1   = (const float*)d_in[7];
    const float* pe_b1   = (const float*)d_in[8];
    const float* pe_w2   = (const float*)d_in[9];
    const float* pe_b2   = (const float*)d_in[10];
    const float* conv1_w = (const float*)d_in[11];
    const float* conv1_b = (const float*)d_in[12];
    const float* conv2_w = (const float*)d_in[13];
    const float* conv2_b = (const float*)d_in[14];
    const float* off_w   = (const float*)d_in[15];
    const float* off_b   = (const float*)d_in[16];
    const float* sw_w    = (const float*)d_in[17];
    const float* sw_b    = (const float*)d_in[18];
    const float* cp_w1   = (const float*)d_in[19];
    const float* cp_b1   = (const float*)d_in[20];
    const float* cp_w2   = (const float*)d_in[21];
    const float* cp_b2   = (const float*)d_in[22];
    const float* cp_w3   = (const float*)d_in[23];
    const float* cp_b3   = (const float*)d_in[24];
    const float* ffn_w1  = (const float*)d_in[25];
    const float* ffn_b1  = (const float*)d_in[26];
    const float* ffn_w2  = (const float*)d_in[27];
    const float* ffn_b2  = (const float*)d_in[28];
    const float* n1g = (const float*)d_in[29];
    const float* n1b = (const float*)d_in[30];
    const float* n2g = (const float*)d_in[31];
    const float* n2b = (const float*)d_in[32];
    const float* n3g = (const float*)d_in[33];
    const float* n3b = (const float*)d_in[34];

    // ---- workspace layout (float units) ----
    float* base   = (float*)d_ws;
    float* pos    = base;                                  //  5,128,192
    u16*   bq16   = (u16*)(base + 5128192);                //  bev_q bf16 snapshot
    float* hbuf   = base + 10256384;                       // 10,256,384 (h1 fp8; alias: ent4)
    u8*    h18    = (u8*)hbuf;                             // [40064][512] fp8
    uint4* ent4   = (uint4*)hbuf;                          // 8 x 160000 x 16B = 20.5MB
    u16*   q16    = (u16*)(base + 20512768);               //  2,564,096
    u16*   qpos16 = (u16*)(base + 23076864);               //  2,564,096 (aliased: cntb)
    int*   cntb   = (int*)qpos16;
    u8*    bufA8  = (u8*)(base + 25640960);                // [40000][128] fp8 (alias: osw)
    float* osw    = (float*)(base + 25640960 + 1310720);   // after bufA8
    u8*    flat8  = (u8*)(base + 28205056);                // [40064][512] fp8
    u8*    ft0    = (u8*)(base + 38461440);                // fp8 features
    u8*    ft1    = ft0 + 6 * 32 * 88 * 128;
    u8*    ft2    = ft1 + 6 * 16 * 44 * 128;
    u8*    ft3    = ft2 + 6 * 8 * 22 * 128;
    u8*    w1t8   = (u8*)(base + 39897600);                // [512][512] fp8
    u8*    w2t8   = w1t8 + 512 * 512;
    u8*    w3t8   = w2t8 + 512 * 512;                      // [128][512] fp8
    u16*   wc1t   = (u16*)(base + 40192512);               // [128][128]
    u16*   wf1t   = (u16*)(base + 40200704);
    u16*   wf2t   = (u16*)(base + 40208896);
    u16*   owsT   = (u16*)(base + 40217088);               // [32][128]
    float* obias  = (float*)(base + 40219136);             // 32
    u8*    wcs8   = (u8*)(base + 40219168);                // 25 x 16KB fp8 frag-major
    u16*   pw2t   = (u16*)(base + 40424168);               // [128][256] bf16
    float* outp   = (float*)d_out;

    // one-time prep
    transpose_feat<<<(6 * 32 * 88 * 32 + 255) / 256, 256, 0, stream>>>(feat0, ft0, 32, 88);
    transpose_feat<<<(6 * 16 * 44 * 32 + 255) / 256, 256, 0, stream>>>(feat1, ft1, 16, 44);
    transpose_feat<<<(6 * 8 * 22 * 32 + 255) / 256, 256, 0, stream>>>(feat2, ft2, 8, 22);
    transpose_feat<<<(6 * 4 * 11 * 32 + 255) / 256, 256, 0, stream>>>(feat3, ft3, 4, 11);
    prep_wt_f8<<<(512 * 512 + 255) / 256, 256, 0, stream>>>(cp_w1, w1t8, 512, 512);
    prep_wt_f8<<<(512 * 512 + 255) / 256, 256, 0, stream>>>(cp_w2, w2t8, 512, 512);
    prep_wt_f8<<<(512 * 128 + 255) / 256, 256, 0, stream>>>(cp_w3, w3t8, 512, 128);
    prep_wt<<<(128 * 128 + 255) / 256, 256, 0, stream>>>(conv1_w, wc1t, 128, 128);
    prep_wt<<<(128 * 128 + 255) / 256, 256, 0, stream>>>(ffn_w1, wf1t, 128, 128);
    prep_wt<<<(128 * 128 + 255) / 256, 256, 0, stream>>>(ffn_w2, wf2t, 128, 128);
    prep_wt<<<(256 * 128 + 255) / 256, 256, 0, stream>>>(pe_w2, pw2t, 256, 128);
    prep_osw_w<<<16, 256, 0, stream>>>(off_w, off_b, sw_w, sw_b, owsT, obias);
    prep_conv_w_f8<<<(51200 + 255) / 256, 256, 0, stream>>>(conv2_w, wcs8);
    prep_cvt16<<<5000, 256, 0, stream>>>(bev_q, bq16, 1280000);
    // position embedding, hid computed in-kernel:
    // pos = relu(bev_pos@W1+b1) @ W2^T + b2 ; qpos16 = bf16(pos + bev_q)
    mfma_pos<<<313, 256, 0, stream>>>(bev_pos, pe_w1, pe_b1, pw2t, pe_b2, bev_q, pos, qpos16);

    for (int layer = 0; layer < 2; layer++){
        const u16* qin16 = layer ? q16 : bq16;
        // in_conv: 1x1 MFMA GEMM + GELU -> fp8, then fp8 5x5 conv + add(bf16) + LN(n1)
        mfma_gemm<128, 2, u8><<<dim3(313, 1), 256, 0, stream>>>(qpos16, wc1t, conv1_b, bufA8, 128);
        conv5_ln<<<625, 256, 0, stream>>>(bufA8, wcs8, conv2_b, qin16, n1g, n1b, q16);
        // off/sw GEMM -> proj (16B entries) -> sampling (fp8 features, fp8 out)
        mfma_osw<<<313, 256, 0, stream>>>(q16, owsT, obias, osw);
        proj_kernel<<<625, 256, 0, stream>>>(osw, bev_pos, l2i, ent4, cntb);
        sample_kernel<<<10000, 256, 0, stream>>>(ent4, cntb, ft0, flat8);
        // compressor MLP (fp8 MFMA): 512->512 relu x2 (same-XCD N-grouping),
        // then fused 512->128 + add(bf16) + LN(n2) -> bf16
        mfma_gemm_f8<512, 1, u8, 4, 313><<<1280, 256, 0, stream>>>(flat8, w1t8, cp_b1, h18, 512);
        mfma_gemm_f8<512, 1, u8, 4, 313><<<1280, 256, 0, stream>>>(h18, w2t8, cp_b2, flat8, 512);
        mfma_gemm_ln_f8<512><<<313, 256, 0, stream>>>(flat8, w3t8, cp_b3, q16, n2g, n2b,
                                                      q16, 40064);
        // fused FFN + add + LN(n3)
        if (layer == 0)
            mfma_ffn_ln<2><<<313, 256, 0, stream>>>(q16, wf1t, ffn_b1, wf2t, ffn_b2,
                                                    q16, n3g, n3b, nullptr, q16, qpos16, pos, 40064);
        else
            mfma_ffn_ln<0><<<313, 256, 0, stream>>>(q16, wf1t, ffn_b1, wf2t, ffn_b2,
                                                    q16, n3g, n3b, outp, nullptr, nullptr, nullptr, 40000);
    }
}

// Round 21
// 421.210 us; speedup vs baseline: 1.0465x; 1.0465x over previous
//
#include <hip/hip_runtime.h>
#include <hip/hip_bf16.h>

typedef unsigned short u16;
typedef unsigned char u8;
typedef __attribute__((ext_vector_type(8))) short bf16x8;
typedef __attribute__((ext_vector_type(4))) float f32x4;
typedef __attribute__((ext_vector_type(2))) float f32x2;

#define DEV __device__ __forceinline__

// ---------- bf16 helpers (storage only; math in f32) ----------
DEV float b2f(u16 s){ return __uint_as_float(((unsigned)s) << 16); }
DEV u16 f2b(float f){
    unsigned u = __float_as_uint(f);
    u = u + 0x7fffu + ((u >> 16) & 1u);   // round-to-nearest-even
    return (u16)(u >> 16);
}
// fp8 e4m3 (OCP) helpers
DEV u8 f2f8(float v){
    int r = __builtin_amdgcn_cvt_pk_fp8_f32(v, v, 0, false);
    return (u8)(r & 0xff);
}
DEV unsigned f2f8x4(float a, float b, float c, float d){
    int lo = __builtin_amdgcn_cvt_pk_fp8_f32(a, b, 0, false);
    int r  = __builtin_amdgcn_cvt_pk_fp8_f32(c, d, lo, true);
    return (unsigned)r;
}
DEV void storeElem(float* p, float v){ *p = v; }
DEV void storeElem(u16* p, float v){ *p = f2b(v); }
DEV void storeElem(u8* p, float v){ *p = f2f8(v); }

template<int ACT> DEV float actf(float x){
    if (ACT == 1) return fmaxf(x, 0.f);
    if (ACT == 2) return 0.5f * x * (1.f + erff(x * 0.70710678118654752f)); // exact GELU
    return x;
}

// async global(16B/lane) -> LDS (wave-uniform base + lane*16)
DEV void gload16(const void* g, void* l){
    __builtin_amdgcn_global_load_lds(
        (const __attribute__((address_space(1))) void*)g,
        (__attribute__((address_space(3))) void*)l, 16, 0, 0);
}

// ---------- feature transpose: (n,C,H,W) f32 -> (n,H,W,C) fp8 ----------
__global__ void transpose_feat(const float* __restrict__ in, u8* __restrict__ out,
                               int H, int W){
    int total = 6 * H * W * 32;                // 4-channel units
    int lin = blockIdx.x * 256 + threadIdx.x;
    if (lin >= total) return;
    int c4   = (lin & 31) * 4;
    int pix  = lin >> 5;
    int x    = pix % W;
    int rest = pix / W;
    int y    = rest % H;
    int n    = rest / H;
    int HW   = H * W;
    size_t ib = ((size_t)(n * 128 + c4) * H + y) * W + x;
    unsigned v4 = f2f8x4(in[ib], in[ib + (size_t)HW],
                         in[ib + (size_t)2 * HW], in[ib + (size_t)3 * HW]);
    *(unsigned*)&out[(size_t)pix * 128 + c4] = v4;
}

// ---------- one-time weight prep ----------
// W[K][N] f32 -> WT[N][K] bf16
__global__ void prep_wt(const float* __restrict__ w, u16* __restrict__ o, int K, int N){
    int id = blockIdx.x * 256 + threadIdx.x;
    if (id >= K * N) return;
    int n = id / K, k = id % K;
    o[id] = f2b(w[(size_t)k * N + n]);
}
// W[K][N] f32 -> WT[N][K] fp8
__global__ void prep_wt_f8(const float* __restrict__ w, u8* __restrict__ o, int K, int N){
    int id = blockIdx.x * 256 + threadIdx.x;
    if (id >= K * N) return;
    int n = id / K, k = id % K;
    o[id] = f2f8(w[(size_t)k * N + n]);
}
// f32 -> bf16 elementwise (4/thread): bev_q snapshot
__global__ void prep_cvt16(const float* __restrict__ src, u16* __restrict__ dst, int n4){
    int i4 = blockIdx.x * 256 + threadIdx.x;
    if (i4 >= n4) return;
    float4 a = *(const float4*)&src[(size_t)i4 * 4];
    ushort4 v; v.x = f2b(a.x); v.y = f2b(a.y); v.z = f2b(a.z); v.w = f2b(a.w);
    *(ushort4*)&dst[(size_t)i4 * 4] = v;
}
// combined off/sw weight: owsT[32][128], obias[32]
__global__ void prep_osw_w(const float* __restrict__ off_w, const float* __restrict__ off_b,
                           const float* __restrict__ sw_w, const float* __restrict__ sw_b,
                           u16* __restrict__ owsT, float* __restrict__ obias){
    int id = blockIdx.x * 256 + threadIdx.x;   // 32*128 = 4096
    if (id >= 4096) return;
    int n = id >> 7, k = id & 127;
    float w = (n < 12) ? off_w[k * 12 + n] : (n < 28) ? sw_w[k * 16 + (n - 12)] : 0.f;
    owsT[n * 128 + k] = f2b(w);
    if (k == 0) obias[n] = (n < 12) ? off_b[n] : (n < 28) ? sw_b[n - 12] : 0.f;
}
// conv2_w (5,5,128,128)=[tap][ic][oc] f32 -> fragment-major fp8:
// byte offset = tap*16384 + ks*4096 + kg*1024 + oc*8 + j, ic = ks*32 + kg*8 + j
__global__ void prep_conv_w_f8(const float* __restrict__ w, u8* __restrict__ o){
    int id = blockIdx.x * 256 + threadIdx.x;   // 25*128*16 = 51200
    if (id >= 51200) return;
    int slot = id & 15;                        // slot = ks*4 + kg
    int oc   = (id >> 4) & 127;
    int tap  = id >> 11;
    int ks = slot >> 2, kg = slot & 3;
    int ic0 = ks * 32 + kg * 8;
    u8 tmp[8];
#pragma unroll
    for (int j = 0; j < 8; j++)
        tmp[j] = f2f8(w[((size_t)tap * 128 + ic0 + j) * 128 + oc]);
    *(long*)&o[(size_t)tap * 16384 + ks * 4096 + kg * 1024 + oc * 8] = *(long*)tmp;
}
// hid = bf16(relu(bev_pos @ pe_w1 + pe_b1)) : [40000][256]
__global__ void prep_hid(const float* __restrict__ bev_pos,
                         const float* __restrict__ w1, const float* __restrict__ b1,
                         u16* __restrict__ hid){
    int id = blockIdx.x * 256 + threadIdx.x;   // 40000*64
    if (id >= 2560000) return;
    int qi = id >> 6, c4 = (id & 63) * 4;
    float p0 = bev_pos[qi * 3 + 0];
    float p1 = bev_pos[qi * 3 + 1];
    float p2 = bev_pos[qi * 3 + 2];
    ushort4 v;
    u16* vp = (u16*)&v;
#pragma unroll
    for (int j = 0; j < 4; j++){
        int ch = c4 + j;
        float h = p0 * w1[ch] + p1 * w1[256 + ch] + p2 * w1[512 + ch] + b1[ch];
        vp[j] = f2b(fmaxf(h, 0.f));
    }
    *(ushort4*)&hid[(size_t)qi * 256 + c4] = v;
}

// ---------- MFMA GEMM (bf16): C[M,Ntot] = act(A[M,K] @ BT[N,K]^T + bias) ----------
DEV void stage64(const u16* __restrict__ g, int ldk, u16* lds, int wv, int lane){
    const u16* gp = g + (size_t)(lane >> 3) * ldk + (lane & 7) * 8;
#pragma unroll
    for (int j = 0; j < 4; j++){
        int ch = wv + j * 4;                 // 16 chunks of 1KB (8 rows each)
        gload16(gp + (size_t)ch * 8 * ldk, lds + ch * 512);
    }
}
// fp8 staging: 128-row x 64B tile, pre-swizzled source (pair ^= (row>>1)&3)
DEV void stage64f8(const u8* __restrict__ g, int ldk, u8* lds, int wv, int lane){
    int rloc = lane >> 2;
#pragma unroll
    for (int j = 0; j < 2; j++){
        int ch = wv + j * 4;                 // 8 chunks of 1KB (16 rows each)
        int row = ch * 16 + rloc;
        int sp  = (lane & 3) ^ ((row >> 1) & 3);
        gload16(g + (size_t)row * ldk + sp * 16, lds + ch * 1024);
    }
}

// NBY>0: 1-D grid of 8*ceil(NBX/8)*NBY blocks (same-XCD N-grouping).
template<int K, int ACT, typename TOUT, int NBY = 0, int NBX = 0>
__global__ __launch_bounds__(256) void mfma_gemm(
    const u16* __restrict__ A, const u16* __restrict__ BT,
    const float* __restrict__ bias, TOUT* __restrict__ C, int Ntot){
    __shared__ u16 As[2][128 * 64];
    __shared__ u16 Bs[2][128 * 64];
    const int t = threadIdx.x, wv = t >> 6, lane = t & 63;
    int bx, by;
    if (NBY > 0){
        const int gpx = (NBX + 7) / 8;
        int xcd = blockIdx.x & 7, slot = blockIdx.x >> 3;
        bx = xcd * gpx + slot / NBY;
        by = slot % NBY;
        if (bx >= NBX) return;
    } else { bx = blockIdx.x; by = blockIdx.y; }
    const int r0 = bx * 128, n0 = by * 128;
    const int l15 = lane & 15, kg = lane >> 4;
    const int wr = (wv >> 1) * 64, wc = (wv & 1) * 64;
    f32x4 acc[4][4];
#pragma unroll
    for (int r = 0; r < 4; r++)
#pragma unroll
        for (int c = 0; c < 4; c++) acc[r][c] = (f32x4){0.f, 0.f, 0.f, 0.f};

    stage64(A + (size_t)r0 * K, K, As[0], wv, lane);
    stage64(BT + (size_t)n0 * K, K, Bs[0], wv, lane);
    __syncthreads();
    int buf = 0;
    for (int kc = 0; kc < K / 64; kc++){
        if (kc + 1 < K / 64){
            stage64(A + (size_t)r0 * K + (kc + 1) * 64, K, As[buf ^ 1], wv, lane);
            stage64(BT + (size_t)n0 * K + (kc + 1) * 64, K, Bs[buf ^ 1], wv, lane);
        }
#pragma unroll
        for (int ks = 0; ks < 2; ks++){
            bf16x8 af[4], bfr[4];
#pragma unroll
            for (int r = 0; r < 4; r++)
                af[r] = *(const bf16x8*)&As[buf][(wr + r * 16 + l15) * 64 + ks * 32 + kg * 8];
#pragma unroll
            for (int c = 0; c < 4; c++)
                bfr[c] = *(const bf16x8*)&Bs[buf][(wc + c * 16 + l15) * 64 + ks * 32 + kg * 8];
#pragma unroll
            for (int r = 0; r < 4; r++)
#pragma unroll
                for (int c = 0; c < 4; c++)
                    acc[r][c] = __builtin_amdgcn_mfma_f32_16x16x32_bf16(af[r], bfr[c], acc[r][c], 0, 0, 0);
        }
        __syncthreads();
        buf ^= 1;
    }
#pragma unroll
    for (int c = 0; c < 4; c++){
        int gcol = n0 + wc + c * 16 + l15;
        float bb = bias[gcol];
#pragma unroll
        for (int r = 0; r < 4; r++){
#pragma unroll
            for (int reg = 0; reg < 4; reg++){
                int grow = r0 + wr + r * 16 + kg * 4 + reg;
                storeElem(C + (size_t)grow * Ntot + gcol, actf<ACT>(acc[r][c][reg] + bb));
            }
        }
    }
}

// ---------- MFMA GEMM (fp8 e4m3 A/B): same tiling, halved LDS/traffic ----------
template<int K, int ACT, typename TOUT, int NBY = 0, int NBX = 0>
__global__ __launch_bounds__(256) void mfma_gemm_f8(
    const u8* __restrict__ A, const u8* __restrict__ BT,
    const float* __restrict__ bias, TOUT* __restrict__ C, int Ntot){
    __shared__ __align__(16) u8 As[2][128 * 64];
    __shared__ __align__(16) u8 Bs[2][128 * 64];
    const int t = threadIdx.x, wv = t >> 6, lane = t & 63;
    int bx, by;
    if (NBY > 0){
        const int gpx = (NBX + 7) / 8;
        int xcd = blockIdx.x & 7, slot = blockIdx.x >> 3;
        bx = xcd * gpx + slot / NBY;
        by = slot % NBY;
        if (bx >= NBX) return;
    } else { bx = blockIdx.x; by = blockIdx.y; }
    const int r0 = bx * 128, n0 = by * 128;
    const int l15 = lane & 15, kg = lane >> 4;
    const int wr = (wv >> 1) * 64, wc = (wv & 1) * 64;
    f32x4 acc[4][4];
#pragma unroll
    for (int r = 0; r < 4; r++)
#pragma unroll
        for (int c = 0; c < 4; c++) acc[r][c] = (f32x4){0.f, 0.f, 0.f, 0.f};

    stage64f8(A + (size_t)r0 * K, K, As[0], wv, lane);
    stage64f8(BT + (size_t)n0 * K, K, Bs[0], wv, lane);
    __syncthreads();
    int buf = 0;
    for (int kc = 0; kc < K / 64; kc++){
        if (kc + 1 < K / 64){
            stage64f8(A + (size_t)r0 * K + (kc + 1) * 64, K, As[buf ^ 1], wv, lane);
            stage64f8(BT + (size_t)n0 * K + (kc + 1) * 64, K, Bs[buf ^ 1], wv, lane);
        }
#pragma unroll
        for (int ks = 0; ks < 2; ks++){
            long af[4], bfr[4];
#pragma unroll
            for (int r = 0; r < 4; r++){
                int row = wr + r * 16 + l15;
                int s8 = (ks * 4 + kg) ^ (row & 6);
                af[r] = *(const long*)&As[buf][row * 64 + s8 * 8];
            }
#pragma unroll
            for (int c = 0; c < 4; c++){
                int row = wc + c * 16 + l15;
                int s8 = (ks * 4 + kg) ^ (row & 6);
                bfr[c] = *(const long*)&Bs[buf][row * 64 + s8 * 8];
            }
#pragma unroll
            for (int r = 0; r < 4; r++)
#pragma unroll
                for (int c = 0; c < 4; c++)
                    acc[r][c] = __builtin_amdgcn_mfma_f32_16x16x32_fp8_fp8(af[r], bfr[c], acc[r][c], 0, 0, 0);
        }
        __syncthreads();
        buf ^= 1;
    }
#pragma unroll
    for (int c = 0; c < 4; c++){
        int gcol = n0 + wc + c * 16 + l15;
        float bb = bias[gcol];
#pragma unroll
        for (int r = 0; r < 4; r++){
#pragma unroll
            for (int reg = 0; reg < 4; reg++){
                int grow = r0 + wr + r * 16 + kg * 4 + reg;
                storeElem(C + (size_t)grow * Ntot + gcol, actf<ACT>(acc[r][c][reg] + bb));
            }
        }
    }
}

// ---------- pos-embed GEMM: pos = hid @ W2^T + b2 ; qpos16 = bf16(pos + bev_q) ----------
__global__ __launch_bounds__(256) void mfma_pos(
    const u16* __restrict__ A, const u16* __restrict__ BT,
    const float* __restrict__ bias, const float* __restrict__ bq,
    float* __restrict__ pos, u16* __restrict__ qp16){
    const int K = 256;
    __shared__ u16 As[2][128 * 64];
    __shared__ u16 Bs[2][128 * 64];
    const int t = threadIdx.x, wv = t >> 6, lane = t & 63;
    const int r0 = blockIdx.x * 128;
    const int l15 = lane & 15, kg = lane >> 4;
    const int wr = (wv >> 1) * 64, wc = (wv & 1) * 64;
    f32x4 acc[4][4];
#pragma unroll
    for (int r = 0; r < 4; r++)
#pragma unroll
        for (int c = 0; c < 4; c++) acc[r][c] = (f32x4){0.f, 0.f, 0.f, 0.f};

    stage64(A + (size_t)r0 * K, K, As[0], wv, lane);
    stage64(BT, K, Bs[0], wv, lane);
    __syncthreads();
    int buf = 0;
    for (int kc = 0; kc < 4; kc++){
        if (kc + 1 < 4){
            stage64(A + (size_t)r0 * K + (kc + 1) * 64, K, As[buf ^ 1], wv, lane);
            stage64(BT + (kc + 1) * 64, K, Bs[buf ^ 1], wv, lane);
        }
#pragma unroll
        for (int ks = 0; ks < 2; ks++){
            bf16x8 af[4], bfr[4];
#pragma unroll
            for (int r = 0; r < 4; r++)
                af[r] = *(const bf16x8*)&As[buf][(wr + r * 16 + l15) * 64 + ks * 32 + kg * 8];
#pragma unroll
            for (int c = 0; c < 4; c++)
                bfr[c] = *(const bf16x8*)&Bs[buf][(wc + c * 16 + l15) * 64 + ks * 32 + kg * 8];
#pragma unroll
            for (int r = 0; r < 4; r++)
#pragma unroll
                for (int c = 0; c < 4; c++)
                    acc[r][c] = __builtin_amdgcn_mfma_f32_16x16x32_bf16(af[r], bfr[c], acc[r][c], 0, 0, 0);
        }
        __syncthreads();
        buf ^= 1;
    }
#pragma unroll
    for (int c = 0; c < 4; c++){
        int gcol = wc + c * 16 + l15;
        float bb = bias[gcol];
#pragma unroll
        for (int r = 0; r < 4; r++){
#pragma unroll
            for (int reg = 0; reg < 4; reg++){
                int grow = r0 + wr + r * 16 + kg * 4 + reg;
                int growc = min(grow, 39999);          // bev_q is 40000 rows
                float v = acc[r][c][reg] + bb;
                pos[(size_t)grow * 128 + gcol]  = v;
                qp16[(size_t)grow * 128 + gcol] = f2b(v + bq[(size_t)growc * 128 + gcol]);
            }
        }
    }
}

// ---------- fused FFN + residual + LN: out = LN(q + relu(q16@W1+b1)@W2 + b2) ----------
// qin is bf16. AUXM: 0 = write outf f32 (final); 2 = write q16out bf16 + auxpos bf16(o+pos)
template<int AUXM>
__global__ __launch_bounds__(256) void mfma_ffn_ln(
    const u16* __restrict__ A, const u16* __restrict__ W1T,
    const float* __restrict__ b1, const u16* __restrict__ W2T,
    const float* __restrict__ b2, const u16* __restrict__ qin16,
    const float* __restrict__ gam, const float* __restrict__ bet,
    float* __restrict__ outf, u16* __restrict__ q16out, u16* __restrict__ auxpos,
    const float* __restrict__ pos, int Mlim){
    __shared__ u16 As[2][128 * 64];   // A tile, then h
    __shared__ u16 Bs[2][128 * 64];   // W1T, then W2T
    const int t = threadIdx.x, wv = t >> 6, lane = t & 63;
    const int r0 = blockIdx.x * 128;
    const int l15 = lane & 15, kg = lane >> 4;
    const int wr = wv * 32;
    f32x4 acc[2][8];
#pragma unroll
    for (int r = 0; r < 2; r++)
#pragma unroll
        for (int c = 0; c < 8; c++) acc[r][c] = (f32x4){0.f, 0.f, 0.f, 0.f};

    stage64(A + (size_t)r0 * 128, 128, As[0], wv, lane);
    stage64(A + (size_t)r0 * 128 + 64, 128, As[1], wv, lane);
    stage64(W1T, 128, Bs[0], wv, lane);
    stage64(W1T + 64, 128, Bs[1], wv, lane);
    __syncthreads();
    // GEMM1: h_acc = A @ W1^T
#pragma unroll
    for (int kc = 0; kc < 2; kc++){
#pragma unroll
        for (int ks = 0; ks < 2; ks++){
            bf16x8 af[2], bfr[8];
#pragma unroll
            for (int r = 0; r < 2; r++)
                af[r] = *(const bf16x8*)&As[kc][(wr + r * 16 + l15) * 64 + ks * 32 + kg * 8];
#pragma unroll
            for (int c = 0; c < 8; c++)
                bfr[c] = *(const bf16x8*)&Bs[kc][(c * 16 + l15) * 64 + ks * 32 + kg * 8];
#pragma unroll
            for (int r = 0; r < 2; r++)
#pragma unroll
                for (int c = 0; c < 8; c++)
                    acc[r][c] = __builtin_amdgcn_mfma_f32_16x16x32_bf16(af[r], bfr[c], acc[r][c], 0, 0, 0);
        }
    }
    __syncthreads();   // all reads of As/Bs complete
    // stage W2T (async) and write h = relu(acc + b1) into As
    stage64(W2T, 128, Bs[0], wv, lane);
    stage64(W2T + 64, 128, Bs[1], wv, lane);
#pragma unroll
    for (int c = 0; c < 8; c++){
        int col = c * 16 + l15;
        float bb1 = b1[col];
#pragma unroll
        for (int r = 0; r < 2; r++)
#pragma unroll
            for (int reg = 0; reg < 4; reg++){
                int rowl = wr + r * 16 + kg * 4 + reg;
                As[col >> 6][rowl * 64 + (col & 63)] = f2b(fmaxf(acc[r][c][reg] + bb1, 0.f));
            }
    }
    __syncthreads();
    // GEMM2: out = h @ W2^T
#pragma unroll
    for (int r = 0; r < 2; r++)
#pragma unroll
        for (int c = 0; c < 8; c++) acc[r][c] = (f32x4){0.f, 0.f, 0.f, 0.f};
#pragma unroll
    for (int kc = 0; kc < 2; kc++){
#pragma unroll
        for (int ks = 0; ks < 2; ks++){
            bf16x8 af[2], bfr[8];
#pragma unroll
            for (int r = 0; r < 2; r++)
                af[r] = *(const bf16x8*)&As[kc][(wr + r * 16 + l15) * 64 + ks * 32 + kg * 8];
#pragma unroll
            for (int c = 0; c < 8; c++)
                bfr[c] = *(const bf16x8*)&Bs[kc][(c * 16 + l15) * 64 + ks * 32 + kg * 8];
#pragma unroll
            for (int r = 0; r < 2; r++)
#pragma unroll
                for (int c = 0; c < 8; c++)
                    acc[r][c] = __builtin_amdgcn_mfma_f32_16x16x32_bf16(af[r], bfr[c], acc[r][c], 0, 0, 0);
        }
    }
    // epilogue: x = acc + b2 + qin; LN over 128 cols (within wave)
    float bb[8], gg[8], be[8];
#pragma unroll
    for (int c = 0; c < 8; c++){
        int col = c * 16 + l15;
        bb[c] = b2[col]; gg[c] = gam[col]; be[c] = bet[col];
    }
#pragma unroll
    for (int r = 0; r < 2; r++){
#pragma unroll
        for (int reg = 0; reg < 4; reg++){
            int grow = r0 + wr + r * 16 + kg * 4 + reg;
            const u16* qrow = qin16 + (size_t)grow * 128;
            float s = 0.f, q2 = 0.f;
#pragma unroll
            for (int c = 0; c < 8; c++){
                float x = acc[r][c][reg] + bb[c] + b2f(qrow[c * 16 + l15]);
                acc[r][c][reg] = x;
                s += x; q2 += x * x;
            }
#pragma unroll
            for (int m = 8; m >= 1; m >>= 1){
                s  += __shfl_xor(s, m, 64);
                q2 += __shfl_xor(q2, m, 64);
            }
            float mean = s * 0.0078125f;
            float var  = q2 * 0.0078125f - mean * mean;
            float rs   = rsqrtf(var + 1e-5f);
            bool wr_ok = grow < Mlim;
#pragma unroll
            for (int c = 0; c < 8; c++){
                float o = (acc[r][c][reg] - mean) * rs * gg[c] + be[c];
                int col = c * 16 + l15;
                if (wr_ok){
                    if (AUXM == 0){
                        outf[(size_t)grow * 128 + col] = o;
                    } else {
                        q16out[(size_t)grow * 128 + col] = f2b(o);
                        auxpos[(size_t)grow * 128 + col] = f2b(o + pos[(size_t)grow * 128 + col]);
                    }
                }
            }
        }
    }
}

// ---------- MFMA GEMM (fp8 A/B) fused residual(bf16) + LN -> bf16 out ----------
template<int K>
__global__ __launch_bounds__(256) void mfma_gemm_ln_f8(
    const u8* __restrict__ A, const u8* __restrict__ BT,
    const float* __restrict__ bias, const u16* __restrict__ qin16,
    const float* __restrict__ gam, const float* __restrict__ bet,
    u16* __restrict__ q16out, int Mlim){
    __shared__ __align__(16) u8 As[2][128 * 64];
    __shared__ __align__(16) u8 Bs[2][128 * 64];
    const int t = threadIdx.x, wv = t >> 6, lane = t & 63;
    const int r0 = blockIdx.x * 128;
    const int l15 = lane & 15, kg = lane >> 4;
    const int wr = wv * 32;
    f32x4 acc[2][8];
#pragma unroll
    for (int r = 0; r < 2; r++)
#pragma unroll
        for (int c = 0; c < 8; c++) acc[r][c] = (f32x4){0.f, 0.f, 0.f, 0.f};

    stage64f8(A + (size_t)r0 * K, K, As[0], wv, lane);
    stage64f8(BT, K, Bs[0], wv, lane);
    __syncthreads();
    int buf = 0;
    for (int kc = 0; kc < K / 64; kc++){
        if (kc + 1 < K / 64){
            stage64f8(A + (size_t)r0 * K + (kc + 1) * 64, K, As[buf ^ 1], wv, lane);
            stage64f8(BT + (kc + 1) * 64, K, Bs[buf ^ 1], wv, lane);
        }
#pragma unroll
        for (int ks = 0; ks < 2; ks++){
            long af[2], bfr[8];
#pragma unroll
            for (int r = 0; r < 2; r++){
                int row = wr + r * 16 + l15;
                int s8 = (ks * 4 + kg) ^ (row & 6);
                af[r] = *(const long*)&As[buf][row * 64 + s8 * 8];
            }
#pragma unroll
            for (int c = 0; c < 8; c++){
                int row = c * 16 + l15;
                int s8 = (ks * 4 + kg) ^ (row & 6);
                bfr[c] = *(const long*)&Bs[buf][row * 64 + s8 * 8];
            }
#pragma unroll
            for (int r = 0; r < 2; r++)
#pragma unroll
                for (int c = 0; c < 8; c++)
                    acc[r][c] = __builtin_amdgcn_mfma_f32_16x16x32_fp8_fp8(af[r], bfr[c], acc[r][c], 0, 0, 0);
        }
        __syncthreads();
        buf ^= 1;
    }
    float bb[8], gg[8], be[8];
#pragma unroll
    for (int c = 0; c < 8; c++){
        int col = c * 16 + l15;
        bb[c] = bias[col]; gg[c] = gam[col]; be[c] = bet[col];
    }
#pragma unroll
    for (int r = 0; r < 2; r++){
#pragma unroll
        for (int reg = 0; reg < 4; reg++){
            int grow = r0 + wr + r * 16 + kg * 4 + reg;
            const u16* qrow = qin16 + (size_t)grow * 128;
            float s = 0.f, q2 = 0.f;
#pragma unroll
            for (int c = 0; c < 8; c++){
                float x = acc[r][c][reg] + bb[c] + b2f(qrow[c * 16 + l15]);
                acc[r][c][reg] = x;
                s += x; q2 += x * x;
            }
#pragma unroll
            for (int m = 8; m >= 1; m >>= 1){
                s  += __shfl_xor(s, m, 64);
                q2 += __shfl_xor(q2, m, 64);
            }
            float mean = s * 0.0078125f;
            float var  = q2 * 0.0078125f - mean * mean;
            float rs   = rsqrtf(var + 1e-5f);
            bool wr_ok = grow < Mlim;
#pragma unroll
            for (int c = 0; c < 8; c++){
                float o = (acc[r][c][reg] - mean) * rs * gg[c] + be[c];
                if (wr_ok) q16out[(size_t)grow * 128 + c * 16 + l15] = f2b(o);
            }
        }
    }
}

// ---------- small MFMA GEMM: osw[M][32] = q16[M][128] @ owsT[32][128]^T + obias ----------
__global__ __launch_bounds__(256) void mfma_osw(
    const u16* __restrict__ A, const u16* __restrict__ BT,
    const float* __restrict__ bias, float* __restrict__ osw){
    __shared__ u16 As[2][128 * 64];   // [k-half][row*64 + k']
    __shared__ u16 Bs[2][32 * 64];
    const int t = threadIdx.x, wv = t >> 6, lane = t & 63;
    const int r0 = blockIdx.x * 128;
    const int l15 = lane & 15, kg = lane >> 4;
#pragma unroll
    for (int it = 0; it < 8; it++){
        int id = it * 256 + t;
        int row = id >> 4, slot = id & 15;
        uint4 v = *(const uint4*)&A[(size_t)(r0 + row) * 128 + slot * 8];
        *(uint4*)&As[slot >> 3][row * 64 + (slot & 7) * 8] = v;
    }
#pragma unroll
    for (int it = 0; it < 2; it++){
        int id = it * 256 + t;
        if (id < 512){
            int row = id >> 4, slot = id & 15;
            uint4 v = *(const uint4*)&BT[(size_t)row * 128 + slot * 8];
            *(uint4*)&Bs[slot >> 3][row * 64 + (slot & 7) * 8] = v;
        }
    }
    __syncthreads();
    f32x4 acc[2][2];
#pragma unroll
    for (int r = 0; r < 2; r++)
#pragma unroll
        for (int c = 0; c < 2; c++) acc[r][c] = (f32x4){0.f, 0.f, 0.f, 0.f};
#pragma unroll
    for (int ks = 0; ks < 4; ks++){
        int h = ks >> 1, koff = (ks & 1) * 32 + kg * 8;
        bf16x8 af[2], bfr[2];
#pragma unroll
        for (int r = 0; r < 2; r++)
            af[r] = *(const bf16x8*)&As[h][(wv * 32 + r * 16 + l15) * 64 + koff];
#pragma unroll
        for (int c = 0; c < 2; c++)
            bfr[c] = *(const bf16x8*)&Bs[h][(c * 16 + l15) * 64 + koff];
#pragma unroll
        for (int r = 0; r < 2; r++)
#pragma unroll
            for (int c = 0; c < 2; c++)
                acc[r][c] = __builtin_amdgcn_mfma_f32_16x16x32_bf16(af[r], bfr[c], acc[r][c], 0, 0, 0);
    }
#pragma unroll
    for (int c = 0; c < 2; c++){
        int gcol = c * 16 + l15;
        float bb = bias[gcol];
#pragma unroll
        for (int r = 0; r < 2; r++)
#pragma unroll
            for (int reg = 0; reg < 4; reg++){
                int grow = r0 + wv * 32 + r * 16 + kg * 4 + reg;
                osw[(size_t)grow * 32 + gcol] = acc[r][c][reg] + bb;
            }
    }
}

// ---------- projection v3: per (q,p) emit 16B entries {bf16 w x4, base, dxdy} ----------
__global__ __launch_bounds__(256) void proj_kernel(
    const float* __restrict__ osw, const float* __restrict__ bev_pos,
    const float* __restrict__ l2i, uint4* __restrict__ ent4, int* __restrict__ cntb){
    int id = blockIdx.x * 256 + threadIdx.x;   // 160000 total
    int qi = id >> 2, p = id & 3;
    const float* row = osw + (size_t)qi * 32;
    float px = bev_pos[qi * 3 + 0] * 100.f - 50.f + row[p * 3 + 0];
    float py = bev_pos[qi * 3 + 1] * 100.f - 50.f + row[p * 3 + 1];
    float pz = bev_pos[qi * 3 + 2] * 8.f   - 5.f  + row[p * 3 + 2];
    float lg[4];
#pragma unroll
    for (int l = 0; l < 4; l++) lg[l] = row[12 + p * 4 + l];
    float mx = fmaxf(fmaxf(lg[0], lg[1]), fmaxf(lg[2], lg[3]));
    float den = 0.f, sw[4];
#pragma unroll
    for (int l = 0; l < 4; l++){ sw[l] = expf(lg[l] - mx); den += sw[l]; }
    float inv = 1.f / den;
#pragma unroll
    for (int l = 0; l < 4; l++) sw[l] *= inv;

    const int HS[4] = {32, 16, 8, 4};
    const int WS[4] = {88, 44, 22, 11};
    const unsigned LOFF[4] = {0u, 2162688u, 2703360u, 2838528u};
    int cnt = 0;
    for (int cam = 0; cam < 6; cam++){
        const float* M = l2i + cam * 16;
        float t0 = M[0] * px + M[1] * py + M[2]  * pz + M[3];
        float t1 = M[4] * px + M[5] * py + M[6]  * pz + M[7];
        float z  = M[8] * px + M[9] * py + M[10] * pz + M[11];
        float zc = fmaxf(z, 1e-5f);
        float u = t0 / (zc * 704.f);
        float v = t1 / (zc * 256.f);
        if (!((z > 1e-5f) && u >= 0.f && u <= 1.f && v >= 0.f && v <= 1.f)) continue;
#pragma unroll
        for (int l = 0; l < 4; l++){
            const int Hl = HS[l], Wl = WS[l];
            float xx = u * (float)Wl - 0.5f;
            float yy = v * (float)Hl - 0.5f;
            float xf = floorf(xx), yf = floorf(yy);
            float wx = xx - xf, wy = yy - yf;
            int ix = (int)xf, iy = (int)yf;
            float sl = sw[l];
            float wx0 = (ix >= 0)      ? 1.f - wx : 0.f;
            float wx1 = (ix < Wl - 1)  ? wx       : 0.f;
            float wy0 = (iy >= 0)      ? 1.f - wy : 0.f;
            float wy1 = (iy < Hl - 1)  ? wy       : 0.f;
            int x0c = max(ix, 0), x1c = min(ix + 1, Wl - 1);
            int y0c = max(iy, 0), y1c = min(iy + 1, Hl - 1);
            unsigned base = LOFF[l] + (unsigned)cam * (unsigned)(Hl * Wl * 128)
                          + (unsigned)(y0c * Wl + x0c) * 128u;
            unsigned dxdy = (unsigned)((x1c - x0c) * 128)
                          | ((unsigned)((y1c - y0c) * Wl * 128) << 16);
            if (cnt < 8){
                uint4 e4;
                e4.x = (unsigned)f2b(sl * wx0 * wy0) | ((unsigned)f2b(sl * wx1 * wy0) << 16);
                e4.y = (unsigned)f2b(sl * wx0 * wy1) | ((unsigned)f2b(sl * wx1 * wy1) << 16);
                e4.z = base;
                e4.w = dxdy;
                ent4[(size_t)cnt * 160000 + id] = e4;
                cnt++;
            }
        }
    }
    cntb[id] = cnt;
}

// ---------- deformable sampling v5: fp8 features, 16B entries, 16 lanes/(q,p) ----------
DEV void fma8f8(float* acc, uint2 v, float w){
    f32x2 p0 = __builtin_amdgcn_cvt_pk_f32_fp8(v.x, false);
    f32x2 p1 = __builtin_amdgcn_cvt_pk_f32_fp8(v.x, true);
    f32x2 p2 = __builtin_amdgcn_cvt_pk_f32_fp8(v.y, false);
    f32x2 p3 = __builtin_amdgcn_cvt_pk_f32_fp8(v.y, true);
    acc[0] = fmaf(p0.x, w, acc[0]);
    acc[1] = fmaf(p0.y, w, acc[1]);
    acc[2] = fmaf(p1.x, w, acc[2]);
    acc[3] = fmaf(p1.y, w, acc[3]);
    acc[4] = fmaf(p2.x, w, acc[4]);
    acc[5] = fmaf(p2.y, w, acc[5]);
    acc[6] = fmaf(p3.x, w, acc[6]);
    acc[7] = fmaf(p3.y, w, acc[7]);
}

__global__ __launch_bounds__(256) void sample_kernel(
    const uint4* __restrict__ ent4, const int* __restrict__ cntb,
    const u8* __restrict__ ftbase, u8* __restrict__ flat){
    const int t = threadIdx.x;
    const int lane = t & 15;
    const int id = blockIdx.x * 16 + (t >> 4);
    const int d0 = lane * 8;
    const int cnt = cntb[id];
    float acc[8] = {0, 0, 0, 0, 0, 0, 0, 0};

    uint4 evA, evB;
    if (cnt > 0) evA = ent4[(size_t)id];
    for (int e = 0; e < cnt; e++){
        if (e + 1 < cnt) evB = ent4[(size_t)(e + 1) * 160000 + id];
        unsigned base = evA.z + (unsigned)d0;
        unsigned dx = evA.w & 0xffffu, dy = evA.w >> 16;
        uint2 v00 = *(const uint2*)(ftbase + base);
        uint2 v10 = *(const uint2*)(ftbase + base + dx);
        uint2 v01 = *(const uint2*)(ftbase + base + dy);
        uint2 v11 = *(const uint2*)(ftbase + base + dx + dy);
        fma8f8(acc, v00, b2f((u16)(evA.x & 0xffffu)));
        fma8f8(acc, v10, b2f((u16)(evA.x >> 16)));
        fma8f8(acc, v01, b2f((u16)(evA.y & 0xffffu)));
        fma8f8(acc, v11, b2f((u16)(evA.y >> 16)));
        evA = evB;
    }
    uint2 o;
    o.x = f2f8x4(acc[0], acc[1], acc[2], acc[3]);
    o.y = f2f8x4(acc[4], acc[5], acc[6], acc[7]);
    *(uint2*)&flat[(size_t)id * 128 + d0] = o;
}

// ---------- 5x5 conv via fp8 MFMA implicit GEMM, fused residual(bf16) + LN(n1) ----------
// 256 threads = 4 waves. Tile 64 px (8y x 8x) x 128 oc. Grid 25x25 = 625.
// Patch LDS stride 136B (17x8B): bank base = 2*pix mod 32 and the 16-lane A-read
// footprint has pix distinct mod 16 -> conflict-free WITHOUT any swizzle.
// Stores are two 8B ds_writes (<=2-way aliasing = free). [round-20: 41.6 -> ~35us]
#define ALOAD(S, DST) if ((S) < 100){                                                 \
    const int tap_ = (S) >> 2, ks_ = (S) & 3;                                         \
    const int ky_ = tap_ / 5, kx_ = tap_ - ky_ * 5;                                   \
    const int s8_ = ks_ * 4 + kg;                                                     \
    _Pragma("unroll")                                                                 \
    for (int fb = 0; fb < 2; fb++){                                                   \
        _Pragma("unroll")                                                             \
        for (int fp = 0; fp < 2; fp++){                                               \
            int pr_ = fb * 4 + (l15 >> 2) + ky_;                                      \
            int pc_ = fp * 4 + (l15 & 3) + kx_;                                       \
            int pix_ = pr_ * 12 + pc_;                                                \
            DST[fb * 2 + fp] = *(const long*)((const char*)Ps + pix_ * 136 + s8_ * 8);\
        }                                                                             \
    }                                                                                 \
}
#define CMFMA(CURA, CURB) {                                                           \
    _Pragma("unroll")                                                                 \
    for (int fr = 0; fr < 4; fr++){                                                   \
        acc[fr][0] = __builtin_amdgcn_mfma_f32_16x16x32_fp8_fp8(CURA[fr], CURB[0], acc[fr][0], 0, 0, 0); \
        acc[fr][1] = __builtin_amdgcn_mfma_f32_16x16x32_fp8_fp8(CURA[fr], CURB[1], acc[fr][1], 0, 0, 0); \
    }                                                                                 \
}
#define LOADB(S, DST) if ((S) < 100){                                                 \
    const u8* wp_ = wfrag + ((S) >> 2) * 16384 + ((S) & 3) * 4096                     \
                   + kg * 1024 + (wc + l15) * 8;                                      \
    DST[0] = *(const long*)(wp_);                                                     \
    DST[1] = *(const long*)(wp_ + 128);                                               \
}

__global__ __launch_bounds__(256, 4) void conv5_ln(
    const u8* __restrict__ in,      // [200][200][128] fp8 (conv1 output)
    const u8* __restrict__ wfrag,   // frag-major fp8 weights
    const float* __restrict__ bias,
    const u16* __restrict__ qin16,  // residual input (bf16, 40000x128)
    const float* __restrict__ gam, const float* __restrict__ bet,
    u16* __restrict__ q16){
    __shared__ __align__(16) u8 Ps[144 * 136];   // 19584 B, stride-136 layout
    const int t = threadIdx.x, wv = t >> 6, lane = t & 63;
    const int bx = blockIdx.x % 25, by = blockIdx.x / 25;
    const int x0 = bx * 8, y0 = by * 8;
    const int l15 = lane & 15, kg = lane >> 4;
    const int wc = wv * 32;             // wave's 32-oc quarter

    // patch staging: 144 px x 8 slot16 of 16B = 1152 chunks (two 8B LDS writes)
#pragma unroll
    for (int it = 0; it < 5; it++){
        int id = it * 256 + t;
        if (id < 1152){
            int pix = id >> 3, slot = id & 7;
            int pr = pix / 12, pc = pix - pr * 12;
            int gy = y0 + pr - 2, gx = x0 + pc - 2;
            uint4 v = {0u, 0u, 0u, 0u};
            if (gy >= 0 && gy < 200 && gx >= 0 && gx < 200)
                v = *(const uint4*)&in[(size_t)(gy * 200 + gx) * 128 + slot * 16];
            char* dst = (char*)Ps + pix * 136 + slot * 16;
            uint2 lo; lo.x = v.x; lo.y = v.y;
            uint2 hi; hi.x = v.z; hi.y = v.w;
            *(uint2*)dst = lo;
            *(uint2*)(dst + 8) = hi;
        }
    }
    f32x4 acc[4][2];
#pragma unroll
    for (int r = 0; r < 4; r++){
        acc[r][0] = (f32x4){0.f, 0.f, 0.f, 0.f};
        acc[r][1] = (f32x4){0.f, 0.f, 0.f, 0.f};
    }

    // preload B steps 0..2 (depth-3)
    long b0[2], b1[2], b2[2], b3[2];
    LOADB(0, b0); LOADB(1, b1); LOADB(2, b2);
    __syncthreads();

    // preload A step 0
    long aA[4], aB[4];
    ALOAD(0, aA);

    // main loop: 100 quarter-tap steps, no barriers, 4-step unroll
    for (int i = 0; i < 25; i++){
        int s = i * 4;
        LOADB(s + 3, b3); ALOAD(s + 1, aB); CMFMA(aA, b0);
        LOADB(s + 4, b0); ALOAD(s + 2, aA); CMFMA(aB, b1);
        LOADB(s + 5, b1); ALOAD(s + 3, aB); CMFMA(aA, b2);
        LOADB(s + 6, b2); ALOAD(s + 4, aA); CMFMA(aB, b3);
    }
    __syncthreads();   // all waves done reading Ps before overlay

    // ---- fused residual + LayerNorm epilogue (Ps is dead; overlay partials) ----
    float* part = (float*)Ps;   // [64][4 waves][2] f32 = 2KB
    float bb[2], gg[2], be[2];
#pragma unroll
    for (int c = 0; c < 2; c++){
        int oc = wc + c * 16 + l15;
        bb[c] = bias[oc]; gg[c] = gam[oc]; be[c] = bet[oc];
    }
#pragma unroll
    for (int fb = 0; fb < 2; fb++){
#pragma unroll
        for (int fp = 0; fp < 2; fp++){
#pragma unroll
            for (int reg = 0; reg < 4; reg++){
                int py = fb * 4 + kg, px = fp * 4 + reg;
                int lp = py * 8 + px;
                int grow = (y0 + py) * 200 + x0 + px;
                const u16* qrow = qin16 + (size_t)grow * 128;
                float s = 0.f, q2 = 0.f;
#pragma unroll
                for (int c = 0; c < 2; c++){
                    float x = acc[fb * 2 + fp][c][reg] + bb[c] + b2f(qrow[wc + c * 16 + l15]);
                    acc[fb * 2 + fp][c][reg] = x;
                    s += x; q2 += x * x;
                }
#pragma unroll
                for (int msk = 8; msk >= 1; msk >>= 1){
                    s  += __shfl_xor(s, msk, 64);
                    q2 += __shfl_xor(q2, msk, 64);
                }
                if (l15 == 0){
                    part[lp * 8 + wv * 2 + 0] = s;
                    part[lp * 8 + wv * 2 + 1] = q2;
                }
            }
        }
    }
    __syncthreads();
#pragma unroll
    for (int fb = 0; fb < 2; fb++){
#pragma unroll
        for (int fp = 0; fp < 2; fp++){
#pragma unroll
            for (int reg = 0; reg < 4; reg++){
                int py = fb * 4 + kg, px = fp * 4 + reg;
                int lp = py * 8 + px;
                int grow = (y0 + py) * 200 + x0 + px;
                float s  = part[lp * 8 + 0] + part[lp * 8 + 2] + part[lp * 8 + 4] + part[lp * 8 + 6];
                float q2 = part[lp * 8 + 1] + part[lp * 8 + 3] + part[lp * 8 + 5] + part[lp * 8 + 7];
                float mean = s * 0.0078125f;
                float var  = q2 * 0.0078125f - mean * mean;
                float rs   = rsqrtf(var + 1e-5f);
#pragma unroll
                for (int c = 0; c < 2; c++){
                    int oc = wc + c * 16 + l15;
                    float o = (acc[fb * 2 + fp][c][reg] - mean) * rs * gg[c] + be[c];
                    q16[(size_t)grow * 128 + oc] = f2b(o);
                }
            }
        }
    }
}

// =======================================================================
extern "C" void kernel_launch(void* const* d_in, const int* in_sizes, int n_in,
                              void* d_out, int out_size, void* d_ws, size_t ws_size,
                              hipStream_t stream){
    const float* feat0   = (const float*)d_in[0];
    const float* feat1   = (const float*)d_in[1];
    const float* feat2   = (const float*)d_in[2];
    const float* feat3   = (const float*)d_in[3];
    const float* l2i     = (const float*)d_in[4];
    const float* bev_q   = (const float*)d_in[5];
    const float* bev_pos = (const float*)d_in[6];
    const float* pe_w1   = (const float*)d_in[7];
    const float* pe_b1   = (const float*)d_in[8];
    const float* pe_w2   = (const float*)d_in[9];
    const float* pe_b2   = (const float*)d_in[10];
    const float* conv1_w = (const float*)d_in[11];
    const float* conv1_b = (const float*)d_in[12];
    const float* conv2_w = (const float*)d_in[13];
    const float* conv2_b = (const float*)d_in[14];
    const float* off_w   = (const float*)d_in[15];
    const float* off_b   = (const float*)d_in[16];
    const float* sw_w    = (const float*)d_in[17];
    const float* sw_b    = (const float*)d_in[18];
    const float* cp_w1   = (const float*)d_in[19];
    const float* cp_b1   = (const float*)d_in[20];
    const float* cp_w2   = (const float*)d_in[21];
    const float* cp_b2   = (const float*)d_in[22];
    const float* cp_w3   = (const float*)d_in[23];
    const float* cp_b3   = (const float*)d_in[24];
    const float* ffn_w1  = (const float*)d_in[25];
    const float* ffn_b1  = (const float*)d_in[26];
    const float* ffn_w2  = (const float*)d_in[27];
    const float* ffn_b2  = (const float*)d_in[28];
    const float* n1g = (const float*)d_in[29];
    const float* n1b = (const float*)d_in[30];
    const float* n2g = (const float*)d_in[31];
    const float* n2b = (const float*)d_in[32];
    const float* n3g = (const float*)d_in[33];
    const float* n3b = (const float*)d_in[34];

    // ---- workspace layout (float units) ----
    float* base   = (float*)d_ws;
    float* pos    = base;                                  //  5,128,192
    u16*   bq16   = (u16*)(base + 5128192);                //  bev_q bf16 snapshot
    float* hbuf   = base + 10256384;                       // 10,256,384 (h1 fp8; alias: ent4)
    u8*    h18    = (u8*)hbuf;                             // [40064][512] fp8
    uint4* ent4   = (uint4*)hbuf;                          // 8 x 160000 x 16B = 20.5MB
    u16*   q16    = (u16*)(base + 20512768);               //  2,564,096
    u16*   qpos16 = (u16*)(base + 23076864);               //  2,564,096 (aliased: cntb)
    int*   cntb   = (int*)qpos16;
    u8*    bufA8  = (u8*)(base + 25640960);                // [40000][128] fp8 (alias: osw)
    float* osw    = (float*)(base + 25640960 + 1310720);   // after bufA8
    u8*    flat8  = (u8*)(base + 28205056);                // [40064][512] fp8 (prep alias: hid16)
    u16*   hid16  = (u16*)flat8;                           // [40064][256] bf16 (prep only)
    u8*    ft0    = (u8*)(base + 38461440);                // fp8 features
    u8*    ft1    = ft0 + 6 * 32 * 88 * 128;
    u8*    ft2    = ft1 + 6 * 16 * 44 * 128;
    u8*    ft3    = ft2 + 6 * 8 * 22 * 128;
    u8*    w1t8   = (u8*)(base + 39897600);                // [512][512] fp8
    u8*    w2t8   = w1t8 + 512 * 512;
    u8*    w3t8   = w2t8 + 512 * 512;                      // [128][512] fp8
    u16*   wc1t   = (u16*)(base + 40192512);               // [128][128]
    u16*   wf1t   = (u16*)(base + 40200704);
    u16*   wf2t   = (u16*)(base + 40208896);
    u16*   owsT   = (u16*)(base + 40217088);               // [32][128]
    float* obias  = (float*)(base + 40219136);             // 32
    u8*    wcs8   = (u8*)(base + 40219168);                // 25 x 16KB fp8 frag-major
    u16*   pw2t   = (u16*)(base + 40424168);               // [128][256] bf16
    float* outp   = (float*)d_out;

    // one-time prep
    transpose_feat<<<(6 * 32 * 88 * 32 + 255) / 256, 256, 0, stream>>>(feat0, ft0, 32, 88);
    transpose_feat<<<(6 * 16 * 44 * 32 + 255) / 256, 256, 0, stream>>>(feat1, ft1, 16, 44);
    transpose_feat<<<(6 * 8 * 22 * 32 + 255) / 256, 256, 0, stream>>>(feat2, ft2, 8, 22);
    transpose_feat<<<(6 * 4 * 11 * 32 + 255) / 256, 256, 0, stream>>>(feat3, ft3, 4, 11);
    prep_wt_f8<<<(512 * 512 + 255) / 256, 256, 0, stream>>>(cp_w1, w1t8, 512, 512);
    prep_wt_f8<<<(512 * 512 + 255) / 256, 256, 0, stream>>>(cp_w2, w2t8, 512, 512);
    prep_wt_f8<<<(512 * 128 + 255) / 256, 256, 0, stream>>>(cp_w3, w3t8, 512, 128);
    prep_wt<<<(128 * 128 + 255) / 256, 256, 0, stream>>>(conv1_w, wc1t, 128, 128);
    prep_wt<<<(128 * 128 + 255) / 256, 256, 0, stream>>>(ffn_w1, wf1t, 128, 128);
    prep_wt<<<(128 * 128 + 255) / 256, 256, 0, stream>>>(ffn_w2, wf2t, 128, 128);
    prep_wt<<<(256 * 128 + 255) / 256, 256, 0, stream>>>(pe_w2, pw2t, 256, 128);
    prep_osw_w<<<16, 256, 0, stream>>>(off_w, off_b, sw_w, sw_b, owsT, obias);
    prep_conv_w_f8<<<(51200 + 255) / 256, 256, 0, stream>>>(conv2_w, wcs8);
    prep_cvt16<<<5000, 256, 0, stream>>>(bev_q, bq16, 1280000);
    // position embedding via MFMA: hid = bf16(relu(pos@W1+b1));
    // pos = hid @ W2^T + b2 ; qpos16 = bf16(pos + bev_q)  (fused epilogue)
    prep_hid<<<10000, 256, 0, stream>>>(bev_pos, pe_w1, pe_b1, hid16);
    mfma_pos<<<313, 256, 0, stream>>>(hid16, pw2t, pe_b2, bev_q, pos, qpos16);

    for (int layer = 0; layer < 2; layer++){
        const u16* qin16 = layer ? q16 : bq16;
        // in_conv: 1x1 MFMA GEMM + GELU -> fp8, then fp8 5x5 conv + add(bf16) + LN(n1)
        mfma_gemm<128, 2, u8><<<dim3(313, 1), 256, 0, stream>>>(qpos16, wc1t, conv1_b, bufA8, 128);
        conv5_ln<<<625, 256, 0, stream>>>(bufA8, wcs8, conv2_b, qin16, n1g, n1b, q16);
        // off/sw GEMM -> proj (16B entries) -> sampling (fp8 features, fp8 out)
        mfma_osw<<<313, 256, 0, stream>>>(q16, owsT, obias, osw);
        proj_kernel<<<625, 256, 0, stream>>>(osw, bev_pos, l2i, ent4, cntb);
        sample_kernel<<<10000, 256, 0, stream>>>(ent4, cntb, ft0, flat8);
        // compressor MLP (fp8 MFMA): 512->512 relu x2 (same-XCD N-grouping),
        // then fused 512->128 + add(bf16) + LN(n2) -> bf16
        mfma_gemm_f8<512, 1, u8, 4, 313><<<1280, 256, 0, stream>>>(flat8, w1t8, cp_b1, h18, 512);
        mfma_gemm_f8<512, 1, u8, 4, 313><<<1280, 256, 0, stream>>>(h18, w2t8, cp_b2, flat8, 512);
        mfma_gemm_ln_f8<512><<<313, 256, 0, stream>>>(flat8, w3t8, cp_b3, q16, n2g, n2b,
                                                      q16, 40064);
        // fused FFN + add + LN(n3)
        if (layer == 0)
            mfma_ffn_ln<2><<<313, 256, 0, stream>>>(q16, wf1t, ffn_b1, wf2t, ffn_b2,
                                                    q16, n3g, n3b, nullptr, q16, qpos16, pos, 40064);
        else
            mfma_ffn_ln<0><<<313, 256, 0, stream>>>(q16, wf1t, ffn_b1, wf2t, ffn_b2,
                                                    q16, n3g, n3b, outp, nullptr, nullptr, nullptr, 40000);
    }
}